// Round 4
// baseline (38166.724 us; speedup 1.0000x reference)
//
#include <hip/hip_runtime.h>
#include <cmath>

constexpr int NB = 128;     // batch
constexpr int NS = 384;     // seq len
constexpr int NH = 384;     // hidden = input dim
constexpr int NZCOL = 3456; // 4H (gate p) + H (mv) + 4H (gate q)
constexpr int NG4 = 1536;
constexpr int NWG = 216;    // cooperative grid: 54 j-tiles x 4 b-tiles
constexpr int TPB = 512;

__device__ __forceinline__ double clampd(double x, double lo, double hi){ return fmin(fmax(x,lo),hi); }
__device__ __forceinline__ double artanh_(double x){ return atanh(clampd(x, -1.0 + 1e-7, 1.0 - 1e-7)); }
__device__ __forceinline__ double normclip(double s){ return sqrt(fmax(s, 1e-15)); }
__device__ __forceinline__ double wredsumd(double v){
  #pragma unroll
  for (int off = 32; off; off >>= 1) v += __shfl_xor(v, off, 64);
  return v;
}

// ---------------- zero ----------------
__global__ void kzerod(double* p, int n){
  int i = blockIdx.x * 256 + threadIdx.x;
  if (i < n) p[i] = 0.0;
}
__global__ void kzerof(float* p, int n){
  int i = blockIdx.x * 256 + threadIdx.x;
  if (i < n) p[i] = 0.f;
}

// ---------------- pack weights: WT[c][j] ----------------
// j in [0,1536): gates from W_all; [1536,1920): W_d; [1920,3456): U_all
__global__ void kprep(const float* __restrict__ W_all, const float* __restrict__ W_d,
                      const float* __restrict__ U_all, float* __restrict__ WT)
{
  int i = blockIdx.x * 256 + threadIdx.x;
  const int nWT = NH * NZCOL;
  if (i >= nWT) return;
  int c = i / NZCOL, j = i % NZCOL;
  float v;
  if (j < NG4){ int g = j / NH, r = j % NH; v = W_all[r * 1536 + g * NH + c]; }
  else if (j < 1920){ int r = j - NG4; v = W_d[r * NH + c]; }
  else { int jj = j - 1920; int g = jj / NH, r = jj % NH; v = U_all[(g * NH + r) * NH + c]; }
  WT[i] = v;
}

// ---------------- device-scope group barrier (all NWG wgs) ----------------
__device__ __forceinline__ void gbar(unsigned* bar, unsigned target){
  __syncthreads();
  if (threadIdx.x == 0){
    __hip_atomic_fetch_add(bar, 1u, __ATOMIC_RELEASE, __HIP_MEMORY_SCOPE_AGENT);
    while (__hip_atomic_load(bar, __ATOMIC_ACQUIRE, __HIP_MEMORY_SCOPE_AGENT) < target)
      __builtin_amdgcn_s_sleep(1);
  }
  __syncthreads();
}

// ---------------- per-step nonlinear, one wave per batch row (device fn) ----------------
__device__ void knl_wave(int ln, int b, int t, const float* __restrict__ Z,
    float* __restrict__ Hs, float* __restrict__ CCs, float* __restrict__ ctx,
    const float* __restrict__ xin, const float* __restrict__ tstamps)
{
  const float* zb = Z + (size_t)b * NZCOL;
  const float* qb = zb + 1920;
  double ts = (double)tstamps[b * NS + t];
  float tsf = (float)ts;

  float cc6[6], mv6[6];
  double s_cc = 0, s_h = 0, s_mv = 0, s_x = 0;
  #pragma unroll
  for (int i = 0; i < 6; ++i){
    int r = ln + 64 * i;
    float c_ = CCs[b * NH + r]; cc6[i] = c_; s_cc += (double)c_ * c_;
    float h_ = Hs[b * NH + r];  s_h += (double)h_ * h_;
    float m_ = zb[NG4 + r];     mv6[i] = m_; s_mv += (double)m_ * m_;
    float x_ = xin[((size_t)b * NS + t) * NH + r]; s_x += (double)x_ * x_;
  }
  double cc2 = wredsumd(s_cc);  double cn = normclip(cc2);
  double hn  = normclip(wredsumd(s_h));
  double mvn = normclip(wredsumd(s_mv));
  double xn  = normclip(wredsumd(s_x));

  // ---- c path ----
  double s1 = tanh(mvn / cn * artanh_(cn));
  float c1f = (float)(s1 / mvn);
  float m1[6]; double sm1 = 0;
  #pragma unroll
  for (int i = 0; i < 6; ++i){ m1[i] = c1f * mv6[i]; sm1 += (double)m1[i] * m1[i]; }
  double n1 = normclip(wredsumd(sm1));
  float l1f = (float)(artanh_(n1) / n1);
  float v6[6]; double sv = 0;
  #pragma unroll
  for (int i = 0; i < 6; ++i){ v6[i] = tanhf(l1f * m1[i]); sv += (double)v6[i] * v6[i]; }
  double nv = normclip(wredsumd(sv));
  float e1f = (float)(tanh(nv) / nv);
  float cs1[6]; double scs = 0, sccd = 0;
  #pragma unroll
  for (int i = 0; i < 6; ++i){ cs1[i] = e1f * v6[i]; scs += (double)cs1[i] * cs1[i]; sccd -= (double)cs1[i] * cc6[i]; }

  double xnt = sqrt(fmax(384.0 * ts * ts, 1e-15));
  double swx = 0;
  #pragma unroll
  for (int i = 0; i < 6; ++i){ float w = cs1[i] * tsf; swx += (double)w * w; }
  double wxn1 = normclip(wredsumd(swx));
  double s2c = tanh(wxn1 / xnt * artanh_(xnt)) / wxn1;
  float s2f = (float)(s2c * ts);
  float cs2[6];
  #pragma unroll
  for (int i = 0; i < 6; ++i) cs2[i] = s2f * cs1[i];

  double x2a = wredsumd(scs);
  double xya = wredsumd(sccd);
  double y2a = cc2;
  double dA = fmax(1.0 + 2.0 * xya + x2a * y2a, 1e-15);
  float fXA = (float)((1.0 + 2.0 * xya + y2a) / dA);
  float fYA = (float)((1.0 - x2a) / dA);
  float A6[6]; double sA = 0, sAc = 0, sc2 = 0;
  #pragma unroll
  for (int i = 0; i < 6; ++i){
    A6[i] = fXA * (-cs1[i]) + fYA * cc6[i];
    sA += (double)A6[i] * A6[i]; sAc += (double)A6[i] * cs2[i]; sc2 += (double)cs2[i] * cs2[i];
  }
  double x2b = wredsumd(sA), xyb = wredsumd(sAc), y2b = wredsumd(sc2);
  double dB = fmax(1.0 + 2.0 * xyb + x2b * y2b, 1e-15);
  float fXB = (float)((1.0 + 2.0 * xyb + y2b) / dB);
  float fYB = (float)((1.0 - x2b) / dB);
  float cadj[6];
  #pragma unroll
  for (int i = 0; i < 6; ++i) cadj[i] = fXB * A6[i] + fYB * cs2[i];

  // ---- gates f,i,o,ct ----
  double art_hn = artanh_(hn), art_xn = artanh_(xn);
  float gates[4][6];
  #pragma unroll 2
  for (int g = 0; g < 4; ++g){
    float pg[6], qg[6]; double s_p = 0, s_q = 0;
    #pragma unroll
    for (int i = 0; i < 6; ++i){
      int r = ln + 64 * i;
      pg[i] = zb[g * NH + r];  s_p += (double)pg[i] * pg[i];
      qg[i] = qb[g * NH + r];  s_q += (double)qg[i] * qg[i];
    }
    double pn = normclip(wredsumd(s_p));
    double qn = normclip(wredsumd(s_q));
    float saf = (float)(tanh(pn / hn * art_hn) / pn);
    float sbf = (float)(tanh(qn / xn * art_xn) / qn);
    float a6[6], b6[6]; double sx2 = 0, sy2 = 0, sxy = 0;
    #pragma unroll
    for (int i = 0; i < 6; ++i){
      a6[i] = saf * pg[i]; b6[i] = sbf * qg[i];
      sx2 += (double)a6[i] * a6[i]; sy2 += (double)b6[i] * b6[i]; sxy += (double)a6[i] * b6[i];
    }
    sx2 = wredsumd(sx2); sy2 = wredsumd(sy2); sxy = wredsumd(sxy);
    double dd = fmax(1.0 + 2.0 * sxy + sx2 * sy2, 1e-15);
    float fX = (float)((1.0 + 2.0 * sxy + sy2) / dd);
    float fY = (float)((1.0 - sx2) / dd);
    float m6[6]; double smm = 0;
    #pragma unroll
    for (int i = 0; i < 6; ++i){ m6[i] = fX * a6[i] + fY * b6[i]; smm += (double)m6[i] * m6[i]; }
    double nm = normclip(wredsumd(smm));
    float slf = (float)(artanh_(nm) / nm);
    #pragma unroll
    for (int i = 0; i < 6; ++i) gates[g][i] = 1.f / (1.f + expf(-slf * m6[i]));
  }

  // ---- cc_n = mobius_add(pw(i,ct), pw(f,c_adj)) ----
  double sct = 0, sict = 0; float wP[6];
  #pragma unroll
  for (int i = 0; i < 6; ++i){ float ct = gates[3][i]; sct += (double)ct * ct; wP[i] = gates[1][i] * ct; sict += (double)wP[i] * wP[i]; }
  double ctn = normclip(wredsumd(sct));
  double wPn = normclip(wredsumd(sict));
  float sPf = (float)(tanh(wPn / ctn * artanh_(ctn)) / wPn);
  float P6[6]; double sPP = 0;
  #pragma unroll
  for (int i = 0; i < 6; ++i){ P6[i] = sPf * wP[i]; sPP += (double)P6[i] * P6[i]; }
  double sca = 0, sfca = 0; float wQ[6];
  #pragma unroll
  for (int i = 0; i < 6; ++i){ sca += (double)cadj[i] * cadj[i]; wQ[i] = gates[0][i] * cadj[i]; sfca += (double)wQ[i] * wQ[i]; }
  double can = normclip(wredsumd(sca));
  double wQn = normclip(wredsumd(sfca));
  float sQf = (float)(tanh(wQn / can * artanh_(can)) / wQn);
  float Q6[6]; double sQQ = 0, sPQ = 0;
  #pragma unroll
  for (int i = 0; i < 6; ++i){ Q6[i] = sQf * wQ[i]; sQQ += (double)Q6[i] * Q6[i]; sPQ += (double)P6[i] * Q6[i]; }
  double x2c = wredsumd(sPP), y2c = wredsumd(sQQ), xyc = wredsumd(sPQ);
  double dC = fmax(1.0 + 2.0 * xyc + x2c * y2c, 1e-15);
  float fXC = (float)((1.0 + 2.0 * xyc + y2c) / dC);
  float fYC = (float)((1.0 - x2c) / dC);
  float ccn6[6], w6[6]; double sw_ = 0;
  #pragma unroll
  for (int i = 0; i < 6; ++i){ ccn6[i] = fXC * P6[i] + fYC * Q6[i]; w6[i] = tanhf(ccn6[i]); sw_ += (double)w6[i] * w6[i]; }
  double nw = normclip(wredsumd(sw_));
  float eef = (float)(tanh(nw) / nw);
  float e6[6], wH[6]; double se = 0, soe = 0;
  #pragma unroll
  for (int i = 0; i < 6; ++i){ e6[i] = eef * w6[i]; se += (double)e6[i] * e6[i]; wH[i] = gates[2][i] * e6[i]; soe += (double)wH[i] * wH[i]; }
  double en = normclip(wredsumd(se));
  double wHn = normclip(wredsumd(soe));
  float sHf = (float)(tanh(wHn / en * artanh_(en)) / wHn);
  #pragma unroll
  for (int i = 0; i < 6; ++i){
    int r = ln + 64 * i;
    CCs[b * NH + r] = ccn6[i];
    Hs[b * NH + r] = sHf * wH[i];
    ctx[((size_t)b * NS + t) * NH + r] = gates[2][i];
  }
}

// ---------------- fused persistent scan: one cooperative launch ----------------
// 216 wgs x 512 thr. wg -> (jt 0..53, bt 0..3) via XCD-grouping swizzle so wgs on
// one XCD (blockIdx%8 heuristic) share a ~790 KB weight slice (L2-resident).
// Per step: GEMM phase (Z[b][j] over 64 j x 32 b, A from LDS, W from L2), barrier,
// knl phase (wgs 0..15: 8 waves = 8 batch rows each), barrier.
__global__ __launch_bounds__(TPB) void kscan(const float* __restrict__ WT,
    float* __restrict__ Hs, float* __restrict__ CCs, float* __restrict__ Zb,
    float* __restrict__ ctx, const float* __restrict__ xin,
    const float* __restrict__ tst, unsigned* __restrict__ bar)
{
  int q = (blockIdx.x & 7) * 27 + (blockIdx.x >> 3);
  int jt = q >> 2, bt = q & 3;
  int j0 = jt * 64, b0 = bt * 32;
  int tid = threadIdx.x;
  int tb = tid >> 4, tj = tid & 15;          // 32 b x 16 float4-cols
  __shared__ float As[32][388];               // [b][k], pad 388 -> conflict-free b128
  const float* wpb = WT + j0 + tj * 4;
  int src = (j0 < NG4) ? 0 : (j0 < 1920 ? 1 : 2);   // tile 64 never straddles
  unsigned nb = 0;
  for (int t = 0; t < NS; ++t){
    // stage A[b][k] (coalesced, no transpose)
    for (int u = tid; u < 32 * 96; u += TPB){
      int bb = u / 96, k4 = (u % 96) * 4;
      const float* ar = (src == 0) ? (Hs + (size_t)(b0 + bb) * NH)
                      : (src == 1) ? (CCs + (size_t)(b0 + bb) * NH)
                      : (xin + ((size_t)(b0 + bb) * NS + t) * NH);
      *(float4*)&As[bb][k4] = *(const float4*)(ar + k4);
    }
    __syncthreads();
    // GEMM: z[b0+tb][j0+4tj..+3], 32-k fp32 chunks + fp64 chunk-sum (same as r3)
    double accd[4] = {0,0,0,0};
    for (int k = 0; k < 384; k += 32){
      float acc[4] = {0,0,0,0};
      #pragma unroll
      for (int kk = 0; kk < 32; kk += 4){
        float4 a4 = *(const float4*)&As[tb][k + kk];
        float av[4] = {a4.x, a4.y, a4.z, a4.w};
        #pragma unroll
        for (int u = 0; u < 4; ++u){
          float4 w = *(const float4*)(wpb + (size_t)(k + kk + u) * NZCOL);
          acc[0] += av[u] * w.x; acc[1] += av[u] * w.y;
          acc[2] += av[u] * w.z; acc[3] += av[u] * w.w;
        }
      }
      accd[0] += acc[0]; accd[1] += acc[1]; accd[2] += acc[2]; accd[3] += acc[3];
    }
    float4 o; o.x = (float)accd[0]; o.y = (float)accd[1];
    o.z = (float)accd[2]; o.w = (float)accd[3];
    *(float4*)(Zb + (size_t)(b0 + tb) * NZCOL + j0 + tj * 4) = o;
    gbar(bar, (++nb) * NWG);
    // knl phase: wgs 0..15, wave wv handles b = blockIdx*8+wv
    if (blockIdx.x < 16){
      int wv = tid >> 6, ln = tid & 63;
      knl_wave(ln, blockIdx.x * 8 + wv, t, Zb, Hs, CCs, ctx, xin, tst);
    }
    gbar(bar, (++nb) * NWG);
  }
}

// ---------------- block reduce helpers (256 threads / 4 waves), double ----------------
__device__ __forceinline__ double blocksumd(double v, double* red){
  v = wredsumd(v);
  __syncthreads();
  if ((threadIdx.x & 63) == 0) red[threadIdx.x >> 6] = v;
  __syncthreads();
  return red[0] + red[1] + red[2] + red[3];
}
__device__ __forceinline__ double blockmaxd(double v, double* red){
  #pragma unroll
  for (int off = 32; off; off >>= 1) v = fmax(v, __shfl_xor(v, off, 64));
  __syncthreads();
  if ((threadIdx.x & 63) == 0) red[threadIdx.x >> 6] = v;
  __syncthreads();
  return fmax(fmax(red[0], red[1]), fmax(red[2], red[3]));
}

// ---------------- query / scores / softmax / aw / bt (one block per b) ----------------
__global__ __launch_bounds__(256) void kattn1(const float* __restrict__ Hs,
    const float* __restrict__ Win, const float* __restrict__ ctx,
    const float* __restrict__ dt, const float* __restrict__ ab,
    double* __restrict__ query, double* __restrict__ aw, double* __restrict__ bt)
{
  int b = blockIdx.x; int tid = threadIdx.x;
  __shared__ double hL[NH], qL[NH], sc[NS];
  __shared__ double red[4];
  for (int r = tid; r < NH; r += 256) hL[r] = (double)Hs[b * NH + r];
  __syncthreads();
  for (int r = tid; r < NH; r += 256){
    double s = 0;
    const float* wr = Win + (size_t)r * NH;
    for (int c = 0; c < NH; ++c) s += hL[c] * (double)wr[c];
    qL[r] = s; query[b * NH + r] = s;
  }
  __syncthreads();
  int wv = tid >> 6, ln = tid & 63;
  for (int s_ = wv; s_ < NS; s_ += 4){
    const float* crow = ctx + ((size_t)b * NS + s_) * NH;
    double par = 0;
    #pragma unroll
    for (int i = 0; i < 6; ++i){ int d = ln + 64 * i; par += qL[d] * (double)crow[d]; }
    par = wredsumd(par);
    if (ln == 0) sc[s_] = par;
  }
  __syncthreads();
  double v0 = sc[tid];
  double v1 = (tid + 256 < NS) ? sc[tid + 256] : -1e300;
  double mx = blockmaxd(fmax(v0, v1), red);
  double e0 = exp(v0 - mx);
  double e1 = (tid + 256 < NS) ? exp(v1 - mx) : 0.0;
  double tot = blocksumd(e0 + e1, red);
  double a0 = e0 / tot, a1 = e1 / tot;
  double n = normclip(blocksumd(a0 * a0 + a1 * a1, red));
  double s1 = tanh(n) / n;
  double w0 = s1 * a0, w1 = s1 * a1;
  double pn = normclip(blocksumd(w0 * w0 + w1 * w1, red));
  if (pn > 0.999){ double f = 0.999 / pn; w0 *= f; w1 *= f; }
  aw[b * NS + tid] = w0;
  if (tid + 256 < NS) aw[b * NS + tid + 256] = w1;
  double abv = (double)ab[b];
  double b0 = exp(-abv * (double)dt[b * NS + tid]);
  double b1v = (tid + 256 < NS) ? exp(-abv * (double)dt[b * NS + tid + 256]) : 0.0;
  double nb = normclip(blocksumd(b0 * b0 + b1v * b1v, red));
  double sb = tanh(nb) / nb;
  double c0 = sb * b0, c1 = sb * b1v;
  double pnb = normclip(blocksumd(c0 * c0 + c1 * c1, red));
  if (pnb > 0.999){ double f = 0.999 / pnb; c0 *= f; c1 *= f; }
  bt[b * NS + tid] = c0;
  if (tid + 256 < NS) bt[b * NS + tid + 256] = c1;
}

// ---------------- hyperbolic attention mixing, one block per (b, 32 h-rows) ----------------
__global__ __launch_bounds__(256) void kmix(const float* __restrict__ ctx,
    const double* __restrict__ aw, const double* __restrict__ bt,
    const float* __restrict__ ae, double* __restrict__ nom, double* __restrict__ den)
{
  int b = blockIdx.y; int h0 = blockIdx.x * 32;
  __shared__ float T[32][385];
  int tid = threadIdx.x;
  for (int idx = tid; idx < NS * 32; idx += 256){
    int s = idx >> 5, hh = idx & 31;
    T[hh][s] = ctx[((size_t)b * NS + s) * NH + h0 + hh];
  }
  __syncthreads();
  int wv = tid >> 6, ln = tid & 63;
  double aev = (double)ae[b];
  double aw6[6], bt6[6]; double sbt = 0;
  #pragma unroll
  for (int i = 0; i < 6; ++i){
    aw6[i] = aw[b * NS + ln + 64 * i];
    bt6[i] = bt[b * NS + ln + 64 * i];
    sbt += bt6[i] * bt6[i];
  }
  double xnb = normclip(wredsumd(sbt));
  double art_xnb = artanh_(xnb);
  double denacc = 0.0;
  for (int k = 0; k < 8; ++k){
    int hh = wv * 8 + k;
    double v[6]; double sx = 0;
    #pragma unroll
    for (int i = 0; i < 6; ++i){ v[i] = (double)T[hh][ln + 64 * i]; sx += v[i] * v[i]; }
    double xnv = normclip(wredsumd(sx));
    double wx[6]; double swx = 0;
    #pragma unroll
    for (int i = 0; i < 6; ++i){ wx[i] = aw6[i] * v[i]; swx += wx[i] * wx[i]; }
    double wxn = normclip(wredsumd(swx));
    double s1 = tanh(wxn / xnv * artanh_(xnv)) / wxn;
    double mix[6]; double sm = 0;
    #pragma unroll
    for (int i = 0; i < 6; ++i){ mix[i] = s1 * wx[i]; sm += mix[i] * mix[i]; }
    double n1 = normclip(wredsumd(sm));
    if (n1 > 0.999){ double f = 0.999 / n1;
      #pragma unroll
      for (int i = 0; i < 6; ++i) mix[i] *= f; }
    double sm2 = 0;
    #pragma unroll
    for (int i = 0; i < 6; ++i) sm2 += mix[i] * mix[i];
    double xn2 = normclip(wredsumd(sm2));
    double wx2[6]; double sw2 = 0;
    #pragma unroll
    for (int i = 0; i < 6; ++i){ wx2[i] = aev * mix[i]; sw2 += wx2[i] * wx2[i]; }
    double wxn2 = normclip(wredsumd(sw2));
    double s2 = tanh(wxn2 / xn2 * artanh_(xn2)) / wxn2;
    double tmp[6]; double st = 0;
    #pragma unroll
    for (int i = 0; i < 6; ++i){ tmp[i] = s2 * wx2[i]; st += tmp[i] * tmp[i]; }
    double n2 = normclip(wredsumd(st));
    if (n2 > 0.999){ double f = 0.999 / n2;
      #pragma unroll
      for (int i = 0; i < 6; ++i) tmp[i] *= f; }
    double wx3[6]; double sw3 = 0;
    #pragma unroll
    for (int i = 0; i < 6; ++i){ wx3[i] = tmp[i] * bt6[i]; sw3 += wx3[i] * wx3[i]; }
    double wxn3 = normclip(wredsumd(sw3));
    double s3 = tanh(wxn3 / xnb * art_xnb) / wxn3;
    double t2[6]; double st2 = 0;
    #pragma unroll
    for (int i = 0; i < 6; ++i){ t2[i] = s3 * wx3[i]; st2 += t2[i] * t2[i]; }
    double n3 = normclip(wredsumd(st2));
    if (n3 > 0.999){ double f = 0.999 / n3;
      #pragma unroll
      for (int i = 0; i < 6; ++i) t2[i] *= f; }
    #pragma unroll
    for (int i = 0; i < 6; ++i) t2[i] = fmax(t2[i], 0.0);
    double sxx = 0, syy = 0, sxy = 0;
    #pragma unroll
    for (int i = 0; i < 6; ++i){ sxx += mix[i] * mix[i]; syy += t2[i] * t2[i]; sxy += mix[i] * t2[i]; }
    sxx = wredsumd(sxx); syy = wredsumd(syy); sxy = wredsumd(sxy);
    double dn = fmax(1.0 + 2.0 * sxy + sxx * syy, 1e-15);
    double ca = (1.0 + 2.0 * sxy + syy) / dn, cb = (1.0 - sxx) / dn;
    double m2[6]; double sm3 = 0;
    #pragma unroll
    for (int i = 0; i < 6; ++i){ m2[i] = ca * mix[i] + cb * t2[i]; sm3 += m2[i] * m2[i]; }
    double n4 = normclip(wredsumd(sm3));
    if (n4 > 0.999){ double f = 0.999 / n4;
      #pragma unroll
      for (int i = 0; i < 6; ++i) m2[i] *= f; }
    double snn = 0;
    #pragma unroll
    for (int i = 0; i < 6; ++i) snn += m2[i] * m2[i];
    snn = wredsumd(snn);
    double lam = 2.0 / fmax(1.0 - snn, 1e-15);
    #pragma unroll
    for (int i = 0; i < 6; ++i) atomicAdd(&nom[b * NS + ln + 64 * i], lam * m2[i]);
    if (ln == 0) denacc += lam - 1.0;
  }
  if (ln == 0) atomicAdd(&den[b], denacc);
}

// ---------------- midpoint + logmap0 + output head, one block per b ----------------
__global__ __launch_bounds__(256) void kfinal(const double* __restrict__ nom,
    const double* __restrict__ den, const double* __restrict__ query,
    const float* __restrict__ Wout, const float* __restrict__ W1,
    const float* __restrict__ b1, const float* __restrict__ W2,
    const float* __restrict__ b2, float* __restrict__ out)
{
  int b = blockIdx.x; int tid = threadIdx.x;
  __shared__ double comb[768];
  __shared__ double att[NH];
  __shared__ double x1[NH];
  __shared__ double red[4];
  double dnb = fmax(den[b], 1e-10);
  double u0 = nom[b * NS + tid] / dnb;
  double u1 = (tid + 256 < NS) ? nom[b * NS + tid + 256] / dnb : 0.0;
  double n = normclip(blocksumd(u0 * u0 + u1 * u1, red));
  double sf = tanh(0.5 * artanh_(n)) / n;
  double f0 = sf * u0, f1 = sf * u1;
  double n2 = normclip(blocksumd(f0 * f0 + f1 * f1, red));
  double sl = artanh_(n2) / n2;
  comb[tid] = sl * f0;
  if (tid + 256 < NS) comb[tid + 256] = sl * f1;
  for (int r = tid; r < NH; r += 256) comb[NH + r] = query[b * NH + r];
  __syncthreads();
  for (int r = tid; r < NH; r += 256){
    double s = 0;
    const float* wr = Wout + (size_t)r * 768;
    for (int c = 0; c < 768; ++c) s += comb[c] * (double)wr[c];
    att[r] = tanh(s);
  }
  __syncthreads();
  for (int r = tid; r < NH; r += 256){
    double s = (double)b1[r];
    const float* wr = W1 + (size_t)r * NH;
    for (int c = 0; c < NH; ++c) s += att[c] * (double)wr[c];
    x1[r] = fmax(s, 0.0);
  }
  __syncthreads();
  double p0 = 0, p1 = 0;
  for (int c = tid; c < NH; c += 256){ p0 += x1[c] * (double)W2[c]; p1 += x1[c] * (double)W2[NH + c]; }
  p0 = blocksumd(p0, red);
  p1 = blocksumd(p1, red);
  if (tid == 0){ out[b * 2 + 0] = (float)(p0 + (double)b2[0]); out[b * 2 + 1] = (float)(p1 + (double)b2[1]); }
}

extern "C" void kernel_launch(void* const* d_in, const int* in_sizes, int n_in,
                              void* d_out, int out_size, void* d_ws, size_t ws_size,
                              hipStream_t stream)
{
  const float* inputs  = (const float*)d_in[0];
  const float* tstamps = (const float*)d_in[1];
  const float* delta_t = (const float*)d_in[2];
  const float* W_all   = (const float*)d_in[3];
  const float* U_all   = (const float*)d_in[4];
  const float* W_d     = (const float*)d_in[5];
  const float* Win     = (const float*)d_in[6];
  const float* Wout    = (const float*)d_in[7];
  const float* ae      = (const float*)d_in[8];
  const float* ab      = (const float*)d_in[9];
  const float* W1      = (const float*)d_in[10];
  const float* b1      = (const float*)d_in[11];
  const float* W2      = (const float*)d_in[12];
  const float* b2      = (const float*)d_in[13];
  float* out = (float*)d_out;

  // double region (base 256B-aligned)
  double* wd = (double*)d_ws;
  size_t od = 0;
  double* NOMD  = wd + od; od += (size_t)NB * NS;
  double* DEND  = wd + od; od += (size_t)NB;
  double* QUERY = wd + od; od += (size_t)NB * NH;
  double* AW    = wd + od; od += (size_t)NB * NS;
  double* BT    = wd + od; od += (size_t)NB * NS;
  float* wf = (float*)(wd + od);
  size_t of = 0;
  float* WT   = wf + of; of += (size_t)NH * NZCOL;    // 1,327,104
  float* Zb   = wf + of; of += (size_t)NB * NZCOL;    // 442,368
  float* Hs32 = wf + of; of += (size_t)NB * NH;
  float* CCs32= wf + of; of += (size_t)NB * NH;
  float* CTX  = wf + of; of += (size_t)NB * NS * NH;  // 18,874,368
  unsigned* BAR = (unsigned*)(wf + of);               // 64 u32

  // zero NOMD..DEND (doubles), Hs/CCs (floats), barrier counter
  int nzd = NB * NS + NB;
  hipLaunchKernelGGL(kzerod, dim3((nzd + 255) / 256), dim3(256), 0, stream, NOMD, nzd);
  int nzf = NB * NH * 2;
  hipLaunchKernelGGL(kzerof, dim3((nzf + 255) / 256), dim3(256), 0, stream, Hs32, nzf);
  hipLaunchKernelGGL(kzerof, dim3(1), dim3(256), 0, stream, (float*)BAR, 64);

  int nprep = NH * NZCOL;
  hipLaunchKernelGGL(kprep, dim3((nprep + 255) / 256), dim3(256), 0, stream,
                     W_all, W_d, U_all, WT);

  // fused persistent scan (cooperative: all 216 wgs co-resident)
  {
    const float* wt_ = WT;
    float* hs_ = Hs32; float* cc_ = CCs32; float* zb_ = Zb; float* ctx_ = CTX;
    const float* xin_ = inputs; const float* tst_ = tstamps;
    unsigned* bar_ = BAR;
    void* args[8] = { &wt_, &hs_, &cc_, &zb_, &ctx_, &xin_, &tst_, &bar_ };
    hipLaunchCooperativeKernel((const void*)kscan, dim3(NWG), dim3(TPB), args, 0, stream);
  }

  hipLaunchKernelGGL(kattn1, dim3(128), dim3(256), 0, stream,
                     Hs32, Win, CTX, delta_t, ab, QUERY, AW, BT);
  hipLaunchKernelGGL(kmix, dim3(12, 128), dim3(256), 0, stream, CTX, AW, BT, ae, NOMD, DEND);
  hipLaunchKernelGGL(kfinal, dim3(128), dim3(256), 0, stream,
                     NOMD, DEND, QUERY, Wout, W1, b1, W2, b2, out);
}

// Round 5
// 36631.161 us; speedup vs baseline: 1.0419x; 1.0419x over previous
//
#include <hip/hip_runtime.h>
#include <cmath>

constexpr int NB = 128;     // batch
constexpr int NS = 384;     // seq len
constexpr int NH = 384;     // hidden = input dim
constexpr int NZCOL = 3456; // 4H (gate p) + H (mv) + 4H (gate q)
constexpr int NG4 = 1536;
constexpr int NPROD = 216;  // producer wgs: 54 j-tiles x 4 b-tiles
constexpr int NKNL = 16;    // knl wgs: 8 batch rows each
constexpr int NWG = NPROD + NKNL;  // 232
constexpr int TPB = 512;
constexpr int FSTRIDE = 32; // u32 per flag slot (128B)

__device__ __forceinline__ double clampd(double x, double lo, double hi){ return fmin(fmax(x,lo),hi); }
__device__ __forceinline__ double artanh_(double x){ return atanh(clampd(x, -1.0 + 1e-7, 1.0 - 1e-7)); }
__device__ __forceinline__ double normclip(double s){ return sqrt(fmax(s, 1e-15)); }
__device__ __forceinline__ double wredsumd(double v){
  #pragma unroll
  for (int off = 32; off; off >>= 1) v += __shfl_xor(v, off, 64);
  return v;
}

// ---------------- zero ----------------
__global__ void kzerod(double* p, int n){
  int i = blockIdx.x * 256 + threadIdx.x;
  if (i < n) p[i] = 0.0;
}
__global__ void kzerof(float* p, int n){
  int i = blockIdx.x * 256 + threadIdx.x;
  if (i < n) p[i] = 0.f;
}

// ---------------- pack weights: WT[c][j] ----------------
// j in [0,1536): gates from W_all; [1536,1920): W_d; [1920,3456): U_all
__global__ void kprep(const float* __restrict__ W_all, const float* __restrict__ W_d,
                      const float* __restrict__ U_all, float* __restrict__ WT)
{
  int i = blockIdx.x * 256 + threadIdx.x;
  const int nWT = NH * NZCOL;
  if (i >= nWT) return;
  int c = i / NZCOL, j = i % NZCOL;
  float v;
  if (j < NG4){ int g = j / NH, r = j % NH; v = W_all[r * 1536 + g * NH + c]; }
  else if (j < 1920){ int r = j - NG4; v = W_d[r * NH + c]; }
  else { int jj = j - 1920; int g = jj / NH, r = jj % NH; v = U_all[(g * NH + r) * NH + c]; }
  WT[i] = v;
}

// ---------------- per-step nonlinear, one wave per batch row (device fn) ----------------
__device__ void knl_wave(int ln, int b, int t, const float* __restrict__ Z,
    float* __restrict__ Hs, float* __restrict__ CCs, float* __restrict__ ctx,
    const float* __restrict__ xin, const float* __restrict__ tstamps)
{
  const float* zb = Z + (size_t)b * NZCOL;
  const float* qb = zb + 1920;
  double ts = (double)tstamps[b * NS + t];
  float tsf = (float)ts;

  float cc6[6], mv6[6];
  double s_cc = 0, s_h = 0, s_mv = 0, s_x = 0;
  #pragma unroll
  for (int i = 0; i < 6; ++i){
    int r = ln + 64 * i;
    float c_ = CCs[b * NH + r]; cc6[i] = c_; s_cc += (double)c_ * c_;
    float h_ = Hs[b * NH + r];  s_h += (double)h_ * h_;
    float m_ = zb[NG4 + r];     mv6[i] = m_; s_mv += (double)m_ * m_;
    float x_ = xin[((size_t)b * NS + t) * NH + r]; s_x += (double)x_ * x_;
  }
  double cc2 = wredsumd(s_cc);  double cn = normclip(cc2);
  double hn  = normclip(wredsumd(s_h));
  double mvn = normclip(wredsumd(s_mv));
  double xn  = normclip(wredsumd(s_x));

  // ---- c path ----
  double s1 = tanh(mvn / cn * artanh_(cn));
  float c1f = (float)(s1 / mvn);
  float m1[6]; double sm1 = 0;
  #pragma unroll
  for (int i = 0; i < 6; ++i){ m1[i] = c1f * mv6[i]; sm1 += (double)m1[i] * m1[i]; }
  double n1 = normclip(wredsumd(sm1));
  float l1f = (float)(artanh_(n1) / n1);
  float v6[6]; double sv = 0;
  #pragma unroll
  for (int i = 0; i < 6; ++i){ v6[i] = tanhf(l1f * m1[i]); sv += (double)v6[i] * v6[i]; }
  double nv = normclip(wredsumd(sv));
  float e1f = (float)(tanh(nv) / nv);
  float cs1[6]; double scs = 0, sccd = 0;
  #pragma unroll
  for (int i = 0; i < 6; ++i){ cs1[i] = e1f * v6[i]; scs += (double)cs1[i] * cs1[i]; sccd -= (double)cs1[i] * cc6[i]; }

  double xnt = sqrt(fmax(384.0 * ts * ts, 1e-15));
  double swx = 0;
  #pragma unroll
  for (int i = 0; i < 6; ++i){ float w = cs1[i] * tsf; swx += (double)w * w; }
  double wxn1 = normclip(wredsumd(swx));
  double s2c = tanh(wxn1 / xnt * artanh_(xnt)) / wxn1;
  float s2f = (float)(s2c * ts);
  float cs2[6];
  #pragma unroll
  for (int i = 0; i < 6; ++i) cs2[i] = s2f * cs1[i];

  double x2a = wredsumd(scs);
  double xya = wredsumd(sccd);
  double y2a = cc2;
  double dA = fmax(1.0 + 2.0 * xya + x2a * y2a, 1e-15);
  float fXA = (float)((1.0 + 2.0 * xya + y2a) / dA);
  float fYA = (float)((1.0 - x2a) / dA);
  float A6[6]; double sA = 0, sAc = 0, sc2 = 0;
  #pragma unroll
  for (int i = 0; i < 6; ++i){
    A6[i] = fXA * (-cs1[i]) + fYA * cc6[i];
    sA += (double)A6[i] * A6[i]; sAc += (double)A6[i] * cs2[i]; sc2 += (double)cs2[i] * cs2[i];
  }
  double x2b = wredsumd(sA), xyb = wredsumd(sAc), y2b = wredsumd(sc2);
  double dB = fmax(1.0 + 2.0 * xyb + x2b * y2b, 1e-15);
  float fXB = (float)((1.0 + 2.0 * xyb + y2b) / dB);
  float fYB = (float)((1.0 - x2b) / dB);
  float cadj[6];
  #pragma unroll
  for (int i = 0; i < 6; ++i) cadj[i] = fXB * A6[i] + fYB * cs2[i];

  // ---- gates f,i,o,ct ----
  double art_hn = artanh_(hn), art_xn = artanh_(xn);
  float gates[4][6];
  #pragma unroll 2
  for (int g = 0; g < 4; ++g){
    float pg[6], qg[6]; double s_p = 0, s_q = 0;
    #pragma unroll
    for (int i = 0; i < 6; ++i){
      int r = ln + 64 * i;
      pg[i] = zb[g * NH + r];  s_p += (double)pg[i] * pg[i];
      qg[i] = qb[g * NH + r];  s_q += (double)qg[i] * qg[i];
    }
    double pn = normclip(wredsumd(s_p));
    double qn = normclip(wredsumd(s_q));
    float saf = (float)(tanh(pn / hn * art_hn) / pn);
    float sbf = (float)(tanh(qn / xn * art_xn) / qn);
    float a6[6], b6[6]; double sx2 = 0, sy2 = 0, sxy = 0;
    #pragma unroll
    for (int i = 0; i < 6; ++i){
      a6[i] = saf * pg[i]; b6[i] = sbf * qg[i];
      sx2 += (double)a6[i] * a6[i]; sy2 += (double)b6[i] * b6[i]; sxy += (double)a6[i] * b6[i];
    }
    sx2 = wredsumd(sx2); sy2 = wredsumd(sy2); sxy = wredsumd(sxy);
    double dd = fmax(1.0 + 2.0 * sxy + sx2 * sy2, 1e-15);
    float fX = (float)((1.0 + 2.0 * sxy + sy2) / dd);
    float fY = (float)((1.0 - sx2) / dd);
    float m6[6]; double smm = 0;
    #pragma unroll
    for (int i = 0; i < 6; ++i){ m6[i] = fX * a6[i] + fY * b6[i]; smm += (double)m6[i] * m6[i]; }
    double nm = normclip(wredsumd(smm));
    float slf = (float)(artanh_(nm) / nm);
    #pragma unroll
    for (int i = 0; i < 6; ++i) gates[g][i] = 1.f / (1.f + expf(-slf * m6[i]));
  }

  // ---- cc_n = mobius_add(pw(i,ct), pw(f,c_adj)) ----
  double sct = 0, sict = 0; float wP[6];
  #pragma unroll
  for (int i = 0; i < 6; ++i){ float ct = gates[3][i]; sct += (double)ct * ct; wP[i] = gates[1][i] * ct; sict += (double)wP[i] * wP[i]; }
  double ctn = normclip(wredsumd(sct));
  double wPn = normclip(wredsumd(sict));
  float sPf = (float)(tanh(wPn / ctn * artanh_(ctn)) / wPn);
  float P6[6]; double sPP = 0;
  #pragma unroll
  for (int i = 0; i < 6; ++i){ P6[i] = sPf * wP[i]; sPP += (double)P6[i] * P6[i]; }
  double sca = 0, sfca = 0; float wQ[6];
  #pragma unroll
  for (int i = 0; i < 6; ++i){ sca += (double)cadj[i] * cadj[i]; wQ[i] = gates[0][i] * cadj[i]; sfca += (double)wQ[i] * wQ[i]; }
  double can = normclip(wredsumd(sca));
  double wQn = normclip(wredsumd(sfca));
  float sQf = (float)(tanh(wQn / can * artanh_(can)) / wQn);
  float Q6[6]; double sQQ = 0, sPQ = 0;
  #pragma unroll
  for (int i = 0; i < 6; ++i){ Q6[i] = sQf * wQ[i]; sQQ += (double)Q6[i] * Q6[i]; sPQ += (double)P6[i] * Q6[i]; }
  double x2c = wredsumd(sPP), y2c = wredsumd(sQQ), xyc = wredsumd(sPQ);
  double dC = fmax(1.0 + 2.0 * xyc + x2c * y2c, 1e-15);
  float fXC = (float)((1.0 + 2.0 * xyc + y2c) / dC);
  float fYC = (float)((1.0 - x2c) / dC);
  float ccn6[6], w6[6]; double sw_ = 0;
  #pragma unroll
  for (int i = 0; i < 6; ++i){ ccn6[i] = fXC * P6[i] + fYC * Q6[i]; w6[i] = tanhf(ccn6[i]); sw_ += (double)w6[i] * w6[i]; }
  double nw = normclip(wredsumd(sw_));
  float eef = (float)(tanh(nw) / nw);
  float e6[6], wH[6]; double se = 0, soe = 0;
  #pragma unroll
  for (int i = 0; i < 6; ++i){ e6[i] = eef * w6[i]; se += (double)e6[i] * e6[i]; wH[i] = gates[2][i] * e6[i]; soe += (double)wH[i] * wH[i]; }
  double en = normclip(wredsumd(se));
  double wHn = normclip(wredsumd(soe));
  float sHf = (float)(tanh(wHn / en * artanh_(en)) / wHn);
  #pragma unroll
  for (int i = 0; i < 6; ++i){
    int r = ln + 64 * i;
    CCs[b * NH + r] = ccn6[i];
    Hs[b * NH + r] = sHf * wH[i];
    ctx[((size_t)b * NS + t) * NH + r] = gates[2][i];
  }
}

// ---------------- fused persistent scan with producer/consumer flag sync ----------------
// 232 wgs x 512 thr. wgs [0,216): GEMM producers (54 j-tiles x 4 b-tiles).
// wgs [216,232): knl consumers (8 waves = 8 batch rows each).
// flags: u32 slots at 128B stride. flagA[i]=producer i step stamp; flagB[k]=knl k stamp.
// Producers wait flagB>=t (knl t-1 done), stamp flagA=t+1 after Zb write.
// knl wgs wait all flagA>=t+1, stamp flagB=t+1 after Hs/CCs write. No RMWs, relaxed polls,
// one __threadfence (acquire/release cache ops) per wg per step on each side.
__global__ __launch_bounds__(TPB) void kscan(const float* __restrict__ WT,
    float* __restrict__ Hs, float* __restrict__ CCs, float* __restrict__ Zb,
    float* __restrict__ ctx, const float* __restrict__ xin,
    const float* __restrict__ tst, unsigned* __restrict__ flags)
{
  int tid = threadIdx.x;
  __shared__ float As[32][388];               // [b][k], pad -> conflict-free b128

  if (blockIdx.x < NPROD){
    // ---------------- producer ----------------
    int q = (blockIdx.x & 7) * 27 + (blockIdx.x >> 3);
    int jt = q >> 2, bt = q & 3;
    int j0 = jt * 64, b0 = bt * 32;
    int tb = tid >> 4, tj = tid & 15;          // 32 b x 16 float4-cols
    const float* wpb = WT + j0 + tj * 4;
    int src = (j0 < NG4) ? 0 : (j0 < 1920 ? 1 : 2);   // tile 64 never straddles
    unsigned* myflag = flags + blockIdx.x * FSTRIDE;
    for (int t = 0; t < NS; ++t){
      if (t > 0){
        // wait: all 16 flagB >= t   (relaxed polls, no cache ops)
        for (;;){
          bool bad = (tid < NKNL) &&
            (__hip_atomic_load(flags + (NPROD + tid) * FSTRIDE, __ATOMIC_RELAXED,
                               __HIP_MEMORY_SCOPE_AGENT) < (unsigned)t);
          if (__syncthreads_count(bad) == 0) break;
          __builtin_amdgcn_s_sleep(1);
        }
        if (src != 2) __threadfence();  // acquire: see fresh Hs/CCs (per-wave cache inv)
      }
      // stage A[b][k]
      for (int u = tid; u < 32 * 96; u += TPB){
        int bb = u / 96, k4 = (u % 96) * 4;
        const float* ar = (src == 0) ? (Hs + (size_t)(b0 + bb) * NH)
                        : (src == 1) ? (CCs + (size_t)(b0 + bb) * NH)
                        : (xin + ((size_t)(b0 + bb) * NS + t) * NH);
        *(float4*)&As[bb][k4] = *(const float4*)(ar + k4);
      }
      __syncthreads();
      // GEMM: z[b0+tb][j0+4tj..+3], 32-k fp32 chunks + fp64 chunk-sum
      double accd[4] = {0,0,0,0};
      for (int k = 0; k < 384; k += 32){
        float acc[4] = {0,0,0,0};
        #pragma unroll
        for (int kk = 0; kk < 32; kk += 4){
          float4 a4 = *(const float4*)&As[tb][k + kk];
          float av[4] = {a4.x, a4.y, a4.z, a4.w};
          #pragma unroll
          for (int u = 0; u < 4; ++u){
            float4 w = *(const float4*)(wpb + (size_t)(k + kk + u) * NZCOL);
            acc[0] += av[u] * w.x; acc[1] += av[u] * w.y;
            acc[2] += av[u] * w.z; acc[3] += av[u] * w.w;
          }
        }
        accd[0] += acc[0]; accd[1] += acc[1]; accd[2] += acc[2]; accd[3] += acc[3];
      }
      float4 o; o.x = (float)accd[0]; o.y = (float)accd[1];
      o.z = (float)accd[2]; o.w = (float)accd[3];
      *(float4*)(Zb + (size_t)(b0 + tb) * NZCOL + j0 + tj * 4) = o;
      __syncthreads();                    // drains all wg stores to L2 (vmcnt before barrier)
      if (tid == 0){
        __threadfence();                  // release: push L2 -> coherence point
        __hip_atomic_store(myflag, (unsigned)(t + 1), __ATOMIC_RELAXED,
                           __HIP_MEMORY_SCOPE_AGENT);
      }
    }
  } else {
    // ---------------- knl consumer ----------------
    int kid = blockIdx.x - NPROD;
    int wv = tid >> 6, ln = tid & 63;
    int b = kid * 8 + wv;
    unsigned* myflag = flags + (NPROD + kid) * FSTRIDE;
    for (int t = 0; t < NS; ++t){
      // wait: all 216 flagA >= t+1
      for (;;){
        bool bad = (tid < NPROD) &&
          (__hip_atomic_load(flags + tid * FSTRIDE, __ATOMIC_RELAXED,
                             __HIP_MEMORY_SCOPE_AGENT) < (unsigned)(t + 1));
        if (__syncthreads_count(bad) == 0) break;
        __builtin_amdgcn_s_sleep(1);
      }
      __threadfence();                    // acquire: see fresh Zb
      knl_wave(ln, b, t, Zb, Hs, CCs, ctx, xin, tst);
      __syncthreads();
      if (tid == 0){
        __threadfence();                  // release: push Hs/CCs/ctx
        __hip_atomic_store(myflag, (unsigned)(t + 1), __ATOMIC_RELAXED,
                           __HIP_MEMORY_SCOPE_AGENT);
      }
    }
  }
}

// ---------------- block reduce helpers (256 threads / 4 waves), double ----------------
__device__ __forceinline__ double blocksumd(double v, double* red){
  v = wredsumd(v);
  __syncthreads();
  if ((threadIdx.x & 63) == 0) red[threadIdx.x >> 6] = v;
  __syncthreads();
  return red[0] + red[1] + red[2] + red[3];
}
__device__ __forceinline__ double blockmaxd(double v, double* red){
  #pragma unroll
  for (int off = 32; off; off >>= 1) v = fmax(v, __shfl_xor(v, off, 64));
  __syncthreads();
  if ((threadIdx.x & 63) == 0) red[threadIdx.x >> 6] = v;
  __syncthreads();
  return fmax(fmax(red[0], red[1]), fmax(red[2], red[3]));
}

// ---------------- query / scores / softmax / aw / bt (one block per b) ----------------
__global__ __launch_bounds__(256) void kattn1(const float* __restrict__ Hs,
    const float* __restrict__ Win, const float* __restrict__ ctx,
    const float* __restrict__ dt, const float* __restrict__ ab,
    double* __restrict__ query, double* __restrict__ aw, double* __restrict__ bt)
{
  int b = blockIdx.x; int tid = threadIdx.x;
  __shared__ double hL[NH], qL[NH], sc[NS];
  __shared__ double red[4];
  for (int r = tid; r < NH; r += 256) hL[r] = (double)Hs[b * NH + r];
  __syncthreads();
  for (int r = tid; r < NH; r += 256){
    double s = 0;
    const float* wr = Win + (size_t)r * NH;
    for (int c = 0; c < NH; ++c) s += hL[c] * (double)wr[c];
    qL[r] = s; query[b * NH + r] = s;
  }
  __syncthreads();
  int wv = tid >> 6, ln = tid & 63;
  for (int s_ = wv; s_ < NS; s_ += 4){
    const float* crow = ctx + ((size_t)b * NS + s_) * NH;
    double par = 0;
    #pragma unroll
    for (int i = 0; i < 6; ++i){ int d = ln + 64 * i; par += qL[d] * (double)crow[d]; }
    par = wredsumd(par);
    if (ln == 0) sc[s_] = par;
  }
  __syncthreads();
  double v0 = sc[tid];
  double v1 = (tid + 256 < NS) ? sc[tid + 256] : -1e300;
  double mx = blockmaxd(fmax(v0, v1), red);
  double e0 = exp(v0 - mx);
  double e1 = (tid + 256 < NS) ? exp(v1 - mx) : 0.0;
  double tot = blocksumd(e0 + e1, red);
  double a0 = e0 / tot, a1 = e1 / tot;
  double n = normclip(blocksumd(a0 * a0 + a1 * a1, red));
  double s1 = tanh(n) / n;
  double w0 = s1 * a0, w1 = s1 * a1;
  double pn = normclip(blocksumd(w0 * w0 + w1 * w1, red));
  if (pn > 0.999){ double f = 0.999 / pn; w0 *= f; w1 *= f; }
  aw[b * NS + tid] = w0;
  if (tid + 256 < NS) aw[b * NS + tid + 256] = w1;
  double abv = (double)ab[b];
  double b0 = exp(-abv * (double)dt[b * NS + tid]);
  double b1v = (tid + 256 < NS) ? exp(-abv * (double)dt[b * NS + tid + 256]) : 0.0;
  double nb = normclip(blocksumd(b0 * b0 + b1v * b1v, red));
  double sb = tanh(nb) / nb;
  double c0 = sb * b0, c1 = sb * b1v;
  double pnb = normclip(blocksumd(c0 * c0 + c1 * c1, red));
  if (pnb > 0.999){ double f = 0.999 / pnb; c0 *= f; c1 *= f; }
  bt[b * NS + tid] = c0;
  if (tid + 256 < NS) bt[b * NS + tid + 256] = c1;
}

// ---------------- hyperbolic attention mixing, one block per (b, 32 h-rows) ----------------
__global__ __launch_bounds__(256) void kmix(const float* __restrict__ ctx,
    const double* __restrict__ aw, const double* __restrict__ bt,
    const float* __restrict__ ae, double* __restrict__ nom, double* __restrict__ den)
{
  int b = blockIdx.y; int h0 = blockIdx.x * 32;
  __shared__ float T[32][385];
  int tid = threadIdx.x;
  for (int idx = tid; idx < NS * 32; idx += 256){
    int s = idx >> 5, hh = idx & 31;
    T[hh][s] = ctx[((size_t)b * NS + s) * NH + h0 + hh];
  }
  __syncthreads();
  int wv = tid >> 6, ln = tid & 63;
  double aev = (double)ae[b];
  double aw6[6], bt6[6]; double sbt = 0;
  #pragma unroll
  for (int i = 0; i < 6; ++i){
    aw6[i] = aw[b * NS + ln + 64 * i];
    bt6[i] = bt[b * NS + ln + 64 * i];
    sbt += bt6[i] * bt6[i];
  }
  double xnb = normclip(wredsumd(sbt));
  double art_xnb = artanh_(xnb);
  double denacc = 0.0;
  for (int k = 0; k < 8; ++k){
    int hh = wv * 8 + k;
    double v[6]; double sx = 0;
    #pragma unroll
    for (int i = 0; i < 6; ++i){ v[i] = (double)T[hh][ln + 64 * i]; sx += v[i] * v[i]; }
    double xnv = normclip(wredsumd(sx));
    double wx[6]; double swx = 0;
    #pragma unroll
    for (int i = 0; i < 6; ++i){ wx[i] = aw6[i] * v[i]; swx += wx[i] * wx[i]; }
    double wxn = normclip(wredsumd(swx));
    double s1 = tanh(wxn / xnv * artanh_(xnv)) / wxn;
    double mix[6]; double sm = 0;
    #pragma unroll
    for (int i = 0; i < 6; ++i){ mix[i] = s1 * wx[i]; sm += mix[i] * mix[i]; }
    double n1 = normclip(wredsumd(sm));
    if (n1 > 0.999){ double f = 0.999 / n1;
      #pragma unroll
      for (int i = 0; i < 6; ++i) mix[i] *= f; }
    double sm2 = 0;
    #pragma unroll
    for (int i = 0; i < 6; ++i) sm2 += mix[i] * mix[i];
    double xn2 = normclip(wredsumd(sm2));
    double wx2[6]; double sw2 = 0;
    #pragma unroll
    for (int i = 0; i < 6; ++i){ wx2[i] = aev * mix[i]; sw2 += wx2[i] * wx2[i]; }
    double wxn2 = normclip(wredsumd(sw2));
    double s2 = tanh(wxn2 / xn2 * artanh_(xn2)) / wxn2;
    double tmp[6]; double st = 0;
    #pragma unroll
    for (int i = 0; i < 6; ++i){ tmp[i] = s2 * wx2[i]; st += tmp[i] * tmp[i]; }
    double n2 = normclip(wredsumd(st));
    if (n2 > 0.999){ double f = 0.999 / n2;
      #pragma unroll
      for (int i = 0; i < 6; ++i) tmp[i] *= f; }
    double wx3[6]; double sw3 = 0;
    #pragma unroll
    for (int i = 0; i < 6; ++i){ wx3[i] = tmp[i] * bt6[i]; sw3 += wx3[i] * wx3[i]; }
    double wxn3 = normclip(wredsumd(sw3));
    double s3 = tanh(wxn3 / xnb * art_xnb) / wxn3;
    double t2[6]; double st2 = 0;
    #pragma unroll
    for (int i = 0; i < 6; ++i){ t2[i] = s3 * wx3[i]; st2 += t2[i] * t2[i]; }
    double n3 = normclip(wredsumd(st2));
    if (n3 > 0.999){ double f = 0.999 / n3;
      #pragma unroll
      for (int i = 0; i < 6; ++i) t2[i] *= f; }
    #pragma unroll
    for (int i = 0; i < 6; ++i) t2[i] = fmax(t2[i], 0.0);
    double sxx = 0, syy = 0, sxy = 0;
    #pragma unroll
    for (int i = 0; i < 6; ++i){ sxx += mix[i] * mix[i]; syy += t2[i] * t2[i]; sxy += mix[i] * t2[i]; }
    sxx = wredsumd(sxx); syy = wredsumd(syy); sxy = wredsumd(sxy);
    double dn = fmax(1.0 + 2.0 * sxy + sxx * syy, 1e-15);
    double ca = (1.0 + 2.0 * sxy + syy) / dn, cb = (1.0 - sxx) / dn;
    double m2[6]; double sm3 = 0;
    #pragma unroll
    for (int i = 0; i < 6; ++i){ m2[i] = ca * mix[i] + cb * t2[i]; sm3 += m2[i] * m2[i]; }
    double n4 = normclip(wredsumd(sm3));
    if (n4 > 0.999){ double f = 0.999 / n4;
      #pragma unroll
      for (int i = 0; i < 6; ++i) m2[i] *= f; }
    double snn = 0;
    #pragma unroll
    for (int i = 0; i < 6; ++i) snn += m2[i] * m2[i];
    snn = wredsumd(snn);
    double lam = 2.0 / fmax(1.0 - snn, 1e-15);
    #pragma unroll
    for (int i = 0; i < 6; ++i) atomicAdd(&nom[b * NS + ln + 64 * i], lam * m2[i]);
    if (ln == 0) denacc += lam - 1.0;
  }
  if (ln == 0) atomicAdd(&den[b], denacc);
}

// ---------------- midpoint + logmap0 + output head, one block per b ----------------
__global__ __launch_bounds__(256) void kfinal(const double* __restrict__ nom,
    const double* __restrict__ den, const double* __restrict__ query,
    const float* __restrict__ Wout, const float* __restrict__ W1,
    const float* __restrict__ b1, const float* __restrict__ W2,
    const float* __restrict__ b2, float* __restrict__ out)
{
  int b = blockIdx.x; int tid = threadIdx.x;
  __shared__ double comb[768];
  __shared__ double att[NH];
  __shared__ double x1[NH];
  __shared__ double red[4];
  double dnb = fmax(den[b], 1e-10);
  double u0 = nom[b * NS + tid] / dnb;
  double u1 = (tid + 256 < NS) ? nom[b * NS + tid + 256] / dnb : 0.0;
  double n = normclip(blocksumd(u0 * u0 + u1 * u1, red));
  double sf = tanh(0.5 * artanh_(n)) / n;
  double f0 = sf * u0, f1 = sf * u1;
  double n2 = normclip(blocksumd(f0 * f0 + f1 * f1, red));
  double sl = artanh_(n2) / n2;
  comb[tid] = sl * f0;
  if (tid + 256 < NS) comb[tid + 256] = sl * f1;
  for (int r = tid; r < NH; r += 256) comb[NH + r] = query[b * NH + r];
  __syncthreads();
  for (int r = tid; r < NH; r += 256){
    double s = 0;
    const float* wr = Wout + (size_t)r * 768;
    for (int c = 0; c < 768; ++c) s += comb[c] * (double)wr[c];
    att[r] = tanh(s);
  }
  __syncthreads();
  for (int r = tid; r < NH; r += 256){
    double s = (double)b1[r];
    const float* wr = W1 + (size_t)r * NH;
    for (int c = 0; c < NH; ++c) s += att[c] * (double)wr[c];
    x1[r] = fmax(s, 0.0);
  }
  __syncthreads();
  double p0 = 0, p1 = 0;
  for (int c = tid; c < NH; c += 256){ p0 += x1[c] * (double)W2[c]; p1 += x1[c] * (double)W2[NH + c]; }
  p0 = blocksumd(p0, red);
  p1 = blocksumd(p1, red);
  if (tid == 0){ out[b * 2 + 0] = (float)(p0 + (double)b2[0]); out[b * 2 + 1] = (float)(p1 + (double)b2[1]); }
}

extern "C" void kernel_launch(void* const* d_in, const int* in_sizes, int n_in,
                              void* d_out, int out_size, void* d_ws, size_t ws_size,
                              hipStream_t stream)
{
  const float* inputs  = (const float*)d_in[0];
  const float* tstamps = (const float*)d_in[1];
  const float* delta_t = (const float*)d_in[2];
  const float* W_all   = (const float*)d_in[3];
  const float* U_all   = (const float*)d_in[4];
  const float* W_d     = (const float*)d_in[5];
  const float* Win     = (const float*)d_in[6];
  const float* Wout    = (const float*)d_in[7];
  const float* ae      = (const float*)d_in[8];
  const float* ab      = (const float*)d_in[9];
  const float* W1      = (const float*)d_in[10];
  const float* b1      = (const float*)d_in[11];
  const float* W2      = (const float*)d_in[12];
  const float* b2      = (const float*)d_in[13];
  float* out = (float*)d_out;

  // double region (base 256B-aligned)
  double* wd = (double*)d_ws;
  size_t od = 0;
  double* NOMD  = wd + od; od += (size_t)NB * NS;
  double* DEND  = wd + od; od += (size_t)NB;
  double* QUERY = wd + od; od += (size_t)NB * NH;
  double* AW    = wd + od; od += (size_t)NB * NS;
  double* BT    = wd + od; od += (size_t)NB * NS;
  float* wf = (float*)(wd + od);
  size_t of = 0;
  float* WT   = wf + of; of += (size_t)NH * NZCOL;    // 1,327,104
  float* Zb   = wf + of; of += (size_t)NB * NZCOL;    // 442,368
  float* Hs32 = wf + of; of += (size_t)NB * NH;
  float* CCs32= wf + of; of += (size_t)NB * NH;
  float* CTX  = wf + of; of += (size_t)NB * NS * NH;  // 18,874,368
  unsigned* FLAGS = (unsigned*)(wf + of);             // 232*32 u32 = 29,696 B
  int nflags = NWG * FSTRIDE;

  // zero NOMD..DEND (doubles), Hs/CCs (floats), flags
  int nzd = NB * NS + NB;
  hipLaunchKernelGGL(kzerod, dim3((nzd + 255) / 256), dim3(256), 0, stream, NOMD, nzd);
  int nzf = NB * NH * 2;
  hipLaunchKernelGGL(kzerof, dim3((nzf + 255) / 256), dim3(256), 0, stream, Hs32, nzf);
  hipLaunchKernelGGL(kzerof, dim3((nflags + 255) / 256), dim3(256), 0, stream,
                     (float*)FLAGS, nflags);

  int nprep = NH * NZCOL;
  hipLaunchKernelGGL(kprep, dim3((nprep + 255) / 256), dim3(256), 0, stream,
                     W_all, W_d, U_all, WT);

  // fused persistent scan (cooperative: all 232 wgs co-resident)
  {
    const float* wt_ = WT;
    float* hs_ = Hs32; float* cc_ = CCs32; float* zb_ = Zb; float* ctx_ = CTX;
    const float* xin_ = inputs; const float* tst_ = tstamps;
    unsigned* flg_ = FLAGS;
    void* args[8] = { &wt_, &hs_, &cc_, &zb_, &ctx_, &xin_, &tst_, &flg_ };
    hipLaunchCooperativeKernel((const void*)kscan, dim3(NWG), dim3(TPB), args, 0, stream);
  }

  hipLaunchKernelGGL(kattn1, dim3(128), dim3(256), 0, stream,
                     Hs32, Win, CTX, delta_t, ab, QUERY, AW, BT);
  hipLaunchKernelGGL(kmix, dim3(12, 128), dim3(256), 0, stream, CTX, AW, BT, ae, NOMD, DEND);
  hipLaunchKernelGGL(kfinal, dim3(128), dim3(256), 0, stream,
                     NOMD, DEND, QUERY, Wout, W1, b1, W2, b2, out);
}

// Round 6
// 33382.559 us; speedup vs baseline: 1.1433x; 1.0973x over previous
//
#include <hip/hip_runtime.h>
#include <cmath>

constexpr int NB = 128;     // batch
constexpr int NS = 384;     // seq len
constexpr int NH = 384;     // hidden = input dim
constexpr int NZCOL = 3456; // 4H (gate p) + H (mv) + 4H (gate q)
constexpr int NG4 = 1536;
constexpr int NPROD = 216;  // producer wgs: 54 j-tiles x 4 b-tiles (grid size)
constexpr int NKNL = 128;   // knl overlay: wgs 0..127, wave 0, one batch row each
constexpr int TPB = 512;
constexpr int FSTRIDE = 32; // u32 per flag slot (128B)

__device__ __forceinline__ double clampd(double x, double lo, double hi){ return fmin(fmax(x,lo),hi); }
__device__ __forceinline__ double artanh_(double x){ return atanh(clampd(x, -1.0 + 1e-7, 1.0 - 1e-7)); }
__device__ __forceinline__ double normclip(double s){ return sqrt(fmax(s, 1e-15)); }
__device__ __forceinline__ double wredsumd(double v){
  #pragma unroll
  for (int off = 32; off; off >>= 1) v += __shfl_xor(v, off, 64);
  return v;
}

// ---------------- zero ----------------
__global__ void kzerod(double* p, int n){
  int i = blockIdx.x * 256 + threadIdx.x;
  if (i < n) p[i] = 0.0;
}
__global__ void kzerof(float* p, int n){
  int i = blockIdx.x * 256 + threadIdx.x;
  if (i < n) p[i] = 0.f;
}

// ---------------- pack weights: WT[c][j] ----------------
// j in [0,1536): gates from W_all; [1536,1920): W_d; [1920,3456): U_all
__global__ void kprep(const float* __restrict__ W_all, const float* __restrict__ W_d,
                      const float* __restrict__ U_all, float* __restrict__ WT)
{
  int i = blockIdx.x * 256 + threadIdx.x;
  const int nWT = NH * NZCOL;
  if (i >= nWT) return;
  int c = i / NZCOL, j = i % NZCOL;
  float v;
  if (j < NG4){ int g = j / NH, r = j % NH; v = W_all[r * 1536 + g * NH + c]; }
  else if (j < 1920){ int r = j - NG4; v = W_d[r * NH + c]; }
  else { int jj = j - 1920; int g = jj / NH, r = jj % NH; v = U_all[(g * NH + r) * NH + c]; }
  WT[i] = v;
}

// ---------------- per-step nonlinear, one wave per batch row (device fn) ----------------
__device__ void knl_wave(int ln, int b, int t, const float* __restrict__ Z,
    float* __restrict__ Hs, float* __restrict__ CCs, float* __restrict__ ctx,
    const float* __restrict__ xin, const float* __restrict__ tstamps)
{
  const float* zb = Z + (size_t)b * NZCOL;
  const float* qb = zb + 1920;
  double ts = (double)tstamps[b * NS + t];
  float tsf = (float)ts;

  float cc6[6], mv6[6];
  double s_cc = 0, s_h = 0, s_mv = 0, s_x = 0;
  #pragma unroll
  for (int i = 0; i < 6; ++i){
    int r = ln + 64 * i;
    float c_ = CCs[b * NH + r]; cc6[i] = c_; s_cc += (double)c_ * c_;
    float h_ = Hs[b * NH + r];  s_h += (double)h_ * h_;
    float m_ = zb[NG4 + r];     mv6[i] = m_; s_mv += (double)m_ * m_;
    float x_ = xin[((size_t)b * NS + t) * NH + r]; s_x += (double)x_ * x_;
  }
  double cc2 = wredsumd(s_cc);  double cn = normclip(cc2);
  double hn  = normclip(wredsumd(s_h));
  double mvn = normclip(wredsumd(s_mv));
  double xn  = normclip(wredsumd(s_x));

  // ---- c path ----
  double s1 = tanh(mvn / cn * artanh_(cn));
  float c1f = (float)(s1 / mvn);
  float m1[6]; double sm1 = 0;
  #pragma unroll
  for (int i = 0; i < 6; ++i){ m1[i] = c1f * mv6[i]; sm1 += (double)m1[i] * m1[i]; }
  double n1 = normclip(wredsumd(sm1));
  float l1f = (float)(artanh_(n1) / n1);
  float v6[6]; double sv = 0;
  #pragma unroll
  for (int i = 0; i < 6; ++i){ v6[i] = tanhf(l1f * m1[i]); sv += (double)v6[i] * v6[i]; }
  double nv = normclip(wredsumd(sv));
  float e1f = (float)(tanh(nv) / nv);
  float cs1[6]; double scs = 0, sccd = 0;
  #pragma unroll
  for (int i = 0; i < 6; ++i){ cs1[i] = e1f * v6[i]; scs += (double)cs1[i] * cs1[i]; sccd -= (double)cs1[i] * cc6[i]; }

  double xnt = sqrt(fmax(384.0 * ts * ts, 1e-15));
  double swx = 0;
  #pragma unroll
  for (int i = 0; i < 6; ++i){ float w = cs1[i] * tsf; swx += (double)w * w; }
  double wxn1 = normclip(wredsumd(swx));
  double s2c = tanh(wxn1 / xnt * artanh_(xnt)) / wxn1;
  float s2f = (float)(s2c * ts);
  float cs2[6];
  #pragma unroll
  for (int i = 0; i < 6; ++i) cs2[i] = s2f * cs1[i];

  double x2a = wredsumd(scs);
  double xya = wredsumd(sccd);
  double y2a = cc2;
  double dA = fmax(1.0 + 2.0 * xya + x2a * y2a, 1e-15);
  float fXA = (float)((1.0 + 2.0 * xya + y2a) / dA);
  float fYA = (float)((1.0 - x2a) / dA);
  float A6[6]; double sA = 0, sAc = 0, sc2 = 0;
  #pragma unroll
  for (int i = 0; i < 6; ++i){
    A6[i] = fXA * (-cs1[i]) + fYA * cc6[i];
    sA += (double)A6[i] * A6[i]; sAc += (double)A6[i] * cs2[i]; sc2 += (double)cs2[i] * cs2[i];
  }
  double x2b = wredsumd(sA), xyb = wredsumd(sAc), y2b = wredsumd(sc2);
  double dB = fmax(1.0 + 2.0 * xyb + x2b * y2b, 1e-15);
  float fXB = (float)((1.0 + 2.0 * xyb + y2b) / dB);
  float fYB = (float)((1.0 - x2b) / dB);
  float cadj[6];
  #pragma unroll
  for (int i = 0; i < 6; ++i) cadj[i] = fXB * A6[i] + fYB * cs2[i];

  // ---- gates f,i,o,ct — FULL unroll: 4 independent fp64 chains interleave ----
  double art_hn = artanh_(hn), art_xn = artanh_(xn);
  float gates[4][6];
  #pragma unroll
  for (int g = 0; g < 4; ++g){
    float pg[6], qg[6]; double s_p = 0, s_q = 0;
    #pragma unroll
    for (int i = 0; i < 6; ++i){
      int r = ln + 64 * i;
      pg[i] = zb[g * NH + r];  s_p += (double)pg[i] * pg[i];
      qg[i] = qb[g * NH + r];  s_q += (double)qg[i] * qg[i];
    }
    double pn = normclip(wredsumd(s_p));
    double qn = normclip(wredsumd(s_q));
    float saf = (float)(tanh(pn / hn * art_hn) / pn);
    float sbf = (float)(tanh(qn / xn * art_xn) / qn);
    float a6[6], b6[6]; double sx2 = 0, sy2 = 0, sxy = 0;
    #pragma unroll
    for (int i = 0; i < 6; ++i){
      a6[i] = saf * pg[i]; b6[i] = sbf * qg[i];
      sx2 += (double)a6[i] * a6[i]; sy2 += (double)b6[i] * b6[i]; sxy += (double)a6[i] * b6[i];
    }
    sx2 = wredsumd(sx2); sy2 = wredsumd(sy2); sxy = wredsumd(sxy);
    double dd = fmax(1.0 + 2.0 * sxy + sx2 * sy2, 1e-15);
    float fX = (float)((1.0 + 2.0 * sxy + sy2) / dd);
    float fY = (float)((1.0 - sx2) / dd);
    float m6[6]; double smm = 0;
    #pragma unroll
    for (int i = 0; i < 6; ++i){ m6[i] = fX * a6[i] + fY * b6[i]; smm += (double)m6[i] * m6[i]; }
    double nm = normclip(wredsumd(smm));
    float slf = (float)(artanh_(nm) / nm);
    #pragma unroll
    for (int i = 0; i < 6; ++i) gates[g][i] = 1.f / (1.f + expf(-slf * m6[i]));
  }

  // ---- cc_n = mobius_add(pw(i,ct), pw(f,c_adj)) ----
  double sct = 0, sict = 0; float wP[6];
  #pragma unroll
  for (int i = 0; i < 6; ++i){ float ct = gates[3][i]; sct += (double)ct * ct; wP[i] = gates[1][i] * ct; sict += (double)wP[i] * wP[i]; }
  double ctn = normclip(wredsumd(sct));
  double wPn = normclip(wredsumd(sict));
  float sPf = (float)(tanh(wPn / ctn * artanh_(ctn)) / wPn);
  float P6[6]; double sPP = 0;
  #pragma unroll
  for (int i = 0; i < 6; ++i){ P6[i] = sPf * wP[i]; sPP += (double)P6[i] * P6[i]; }
  double sca = 0, sfca = 0; float wQ[6];
  #pragma unroll
  for (int i = 0; i < 6; ++i){ sca += (double)cadj[i] * cadj[i]; wQ[i] = gates[0][i] * cadj[i]; sfca += (double)wQ[i] * wQ[i]; }
  double can = normclip(wredsumd(sca));
  double wQn = normclip(wredsumd(sfca));
  float sQf = (float)(tanh(wQn / can * artanh_(can)) / wQn);
  float Q6[6]; double sQQ = 0, sPQ = 0;
  #pragma unroll
  for (int i = 0; i < 6; ++i){ Q6[i] = sQf * wQ[i]; sQQ += (double)Q6[i] * Q6[i]; sPQ += (double)P6[i] * Q6[i]; }
  double x2c = wredsumd(sPP), y2c = wredsumd(sQQ), xyc = wredsumd(sPQ);
  double dC = fmax(1.0 + 2.0 * xyc + x2c * y2c, 1e-15);
  float fXC = (float)((1.0 + 2.0 * xyc + y2c) / dC);
  float fYC = (float)((1.0 - x2c) / dC);
  float ccn6[6], w6[6]; double sw_ = 0;
  #pragma unroll
  for (int i = 0; i < 6; ++i){ ccn6[i] = fXC * P6[i] + fYC * Q6[i]; w6[i] = tanhf(ccn6[i]); sw_ += (double)w6[i] * w6[i]; }
  double nw = normclip(wredsumd(sw_));
  float eef = (float)(tanh(nw) / nw);
  float e6[6], wH[6]; double se = 0, soe = 0;
  #pragma unroll
  for (int i = 0; i < 6; ++i){ e6[i] = eef * w6[i]; se += (double)e6[i] * e6[i]; wH[i] = gates[2][i] * e6[i]; soe += (double)wH[i] * wH[i]; }
  double en = normclip(wredsumd(se));
  double wHn = normclip(wredsumd(soe));
  float sHf = (float)(tanh(wHn / en * artanh_(en)) / wHn);
  #pragma unroll
  for (int i = 0; i < 6; ++i){
    int r = ln + 64 * i;
    CCs[b * NH + r] = ccn6[i];
    Hs[b * NH + r] = sHf * wH[i];
    ctx[((size_t)b * NS + t) * NH + r] = gates[2][i];
  }
}

// ---------------- fused persistent scan: 216 wgs, knl overlaid on wgs 0..127 ----------------
// All 216 wgs are GEMM producers (54 j-tiles x 4 b-tiles, XCD swizzle). After stamping
// flagA[t+1], wgs 0..127 wait for all 216 flagA, then WAVE 0 alone runs knl for row
// b = blockIdx (1 wave/CU: no fp64-issue stacking), stamps flagB[t+1]. Producers wait
// all 128 flagB >= t before reading Hs/CCs (x-tile producers skip the wait-fence).
__global__ __launch_bounds__(TPB) void kscan(const float* __restrict__ WT,
    float* __restrict__ Hs, float* __restrict__ CCs, float* __restrict__ Zb,
    float* __restrict__ ctx, const float* __restrict__ xin,
    const float* __restrict__ tst, unsigned* __restrict__ flags)
{
  int tid = threadIdx.x;
  __shared__ float As[32][388];               // [b][k], pad -> conflict-free b128

  int q = (blockIdx.x & 7) * 27 + (blockIdx.x >> 3);
  int jt = q >> 2, bt = q & 3;
  int j0 = jt * 64, b0 = bt * 32;
  int tb = tid >> 4, tj = tid & 15;          // 32 b x 16 float4-cols
  const float* wpb = WT + j0 + tj * 4;
  int src = (j0 < NG4) ? 0 : (j0 < 1920 ? 1 : 2);   // tile 64 never straddles
  unsigned* flagA = flags + blockIdx.x * FSTRIDE;
  unsigned* flagB = flags + (NPROD + blockIdx.x) * FSTRIDE;  // only used if < 128
  bool isknl = (blockIdx.x < NKNL);
  int ln = tid & 63;

  for (int t = 0; t < NS; ++t){
    if (t > 0){
      // wait: all 128 flagB >= t  (knl t-1 done -> Hs/CCs fresh, Zb free to overwrite)
      for (;;){
        bool bad = (tid < NKNL) &&
          (__hip_atomic_load(flags + (NPROD + tid) * FSTRIDE, __ATOMIC_RELAXED,
                             __HIP_MEMORY_SCOPE_AGENT) < (unsigned)t);
        if (__syncthreads_count(bad) == 0) break;
        __builtin_amdgcn_s_sleep(1);
      }
      if (src != 2) __threadfence();  // acquire: see fresh Hs/CCs
    }
    // stage A[b][k]
    for (int u = tid; u < 32 * 96; u += TPB){
      int bb = u / 96, k4 = (u % 96) * 4;
      const float* ar = (src == 0) ? (Hs + (size_t)(b0 + bb) * NH)
                      : (src == 1) ? (CCs + (size_t)(b0 + bb) * NH)
                      : (xin + ((size_t)(b0 + bb) * NS + t) * NH);
      *(float4*)&As[bb][k4] = *(const float4*)(ar + k4);
    }
    __syncthreads();
    // GEMM: z[b0+tb][j0+4tj..+3], 32-k fp32 chunks + fp64 chunk-sum
    double accd[4] = {0,0,0,0};
    for (int k = 0; k < 384; k += 32){
      float acc[4] = {0,0,0,0};
      #pragma unroll
      for (int kk = 0; kk < 32; kk += 4){
        float4 a4 = *(const float4*)&As[tb][k + kk];
        float av[4] = {a4.x, a4.y, a4.z, a4.w};
        #pragma unroll
        for (int u = 0; u < 4; ++u){
          float4 w = *(const float4*)(wpb + (size_t)(k + kk + u) * NZCOL);
          acc[0] += av[u] * w.x; acc[1] += av[u] * w.y;
          acc[2] += av[u] * w.z; acc[3] += av[u] * w.w;
        }
      }
      accd[0] += acc[0]; accd[1] += acc[1]; accd[2] += acc[2]; accd[3] += acc[3];
    }
    float4 o; o.x = (float)accd[0]; o.y = (float)accd[1];
    o.z = (float)accd[2]; o.w = (float)accd[3];
    *(float4*)(Zb + (size_t)(b0 + tb) * NZCOL + j0 + tj * 4) = o;
    __syncthreads();                    // all wg stores drained to L2
    if (tid == 0){
      __threadfence();                  // release: push Zb slice to coherence point
      __hip_atomic_store(flagA, (unsigned)(t + 1), __ATOMIC_RELAXED,
                         __HIP_MEMORY_SCOPE_AGENT);
    }
    // knl overlay: wgs 0..127, wave 0 handles row b = blockIdx
    if (isknl){
      for (;;){
        bool bad = (tid < NPROD) &&
          (__hip_atomic_load(flags + tid * FSTRIDE, __ATOMIC_RELAXED,
                             __HIP_MEMORY_SCOPE_AGENT) < (unsigned)(t + 1));
        if (__syncthreads_count(bad) == 0) break;
        __builtin_amdgcn_s_sleep(1);
      }
      if (tid < 64){
        __threadfence();                // acquire: see fresh Zb (wave 0 only)
        knl_wave(ln, blockIdx.x, t, Zb, Hs, CCs, ctx, xin, tst);
        if (tid == 0){
          __threadfence();              // release: push Hs/CCs row (wave-0 stores)
          __hip_atomic_store(flagB, (unsigned)(t + 1), __ATOMIC_RELAXED,
                             __HIP_MEMORY_SCOPE_AGENT);
        }
      }
    }
  }
}

// ---------------- block reduce helpers (256 threads / 4 waves), double ----------------
__device__ __forceinline__ double blocksumd(double v, double* red){
  v = wredsumd(v);
  __syncthreads();
  if ((threadIdx.x & 63) == 0) red[threadIdx.x >> 6] = v;
  __syncthreads();
  return red[0] + red[1] + red[2] + red[3];
}
__device__ __forceinline__ double blockmaxd(double v, double* red){
  #pragma unroll
  for (int off = 32; off; off >>= 1) v = fmax(v, __shfl_xor(v, off, 64));
  __syncthreads();
  if ((threadIdx.x & 63) == 0) red[threadIdx.x >> 6] = v;
  __syncthreads();
  return fmax(fmax(red[0], red[1]), fmax(red[2], red[3]));
}

// ---------------- query / scores / softmax / aw / bt (one block per b) ----------------
__global__ __launch_bounds__(256) void kattn1(const float* __restrict__ Hs,
    const float* __restrict__ Win, const float* __restrict__ ctx,
    const float* __restrict__ dt, const float* __restrict__ ab,
    double* __restrict__ query, double* __restrict__ aw, double* __restrict__ bt)
{
  int b = blockIdx.x; int tid = threadIdx.x;
  __shared__ double hL[NH], qL[NH], sc[NS];
  __shared__ double red[4];
  for (int r = tid; r < NH; r += 256) hL[r] = (double)Hs[b * NH + r];
  __syncthreads();
  for (int r = tid; r < NH; r += 256){
    double s = 0;
    const float* wr = Win + (size_t)r * NH;
    for (int c = 0; c < NH; ++c) s += hL[c] * (double)wr[c];
    qL[r] = s; query[b * NH + r] = s;
  }
  __syncthreads();
  int wv = tid >> 6, ln = tid & 63;
  for (int s_ = wv; s_ < NS; s_ += 4){
    const float* crow = ctx + ((size_t)b * NS + s_) * NH;
    double par = 0;
    #pragma unroll
    for (int i = 0; i < 6; ++i){ int d = ln + 64 * i; par += qL[d] * (double)crow[d]; }
    par = wredsumd(par);
    if (ln == 0) sc[s_] = par;
  }
  __syncthreads();
  double v0 = sc[tid];
  double v1 = (tid + 256 < NS) ? sc[tid + 256] : -1e300;
  double mx = blockmaxd(fmax(v0, v1), red);
  double e0 = exp(v0 - mx);
  double e1 = (tid + 256 < NS) ? exp(v1 - mx) : 0.0;
  double tot = blocksumd(e0 + e1, red);
  double a0 = e0 / tot, a1 = e1 / tot;
  double n = normclip(blocksumd(a0 * a0 + a1 * a1, red));
  double s1 = tanh(n) / n;
  double w0 = s1 * a0, w1 = s1 * a1;
  double pn = normclip(blocksumd(w0 * w0 + w1 * w1, red));
  if (pn > 0.999){ double f = 0.999 / pn; w0 *= f; w1 *= f; }
  aw[b * NS + tid] = w0;
  if (tid + 256 < NS) aw[b * NS + tid + 256] = w1;
  double abv = (double)ab[b];
  double b0 = exp(-abv * (double)dt[b * NS + tid]);
  double b1v = (tid + 256 < NS) ? exp(-abv * (double)dt[b * NS + tid + 256]) : 0.0;
  double nb = normclip(blocksumd(b0 * b0 + b1v * b1v, red));
  double sb = tanh(nb) / nb;
  double c0 = sb * b0, c1 = sb * b1v;
  double pnb = normclip(blocksumd(c0 * c0 + c1 * c1, red));
  if (pnb > 0.999){ double f = 0.999 / pnb; c0 *= f; c1 *= f; }
  bt[b * NS + tid] = c0;
  if (tid + 256 < NS) bt[b * NS + tid + 256] = c1;
}

// ---------------- hyperbolic attention mixing, one block per (b, 32 h-rows) ----------------
__global__ __launch_bounds__(256) void kmix(const float* __restrict__ ctx,
    const double* __restrict__ aw, const double* __restrict__ bt,
    const float* __restrict__ ae, double* __restrict__ nom, double* __restrict__ den)
{
  int b = blockIdx.y; int h0 = blockIdx.x * 32;
  __shared__ float T[32][385];
  int tid = threadIdx.x;
  for (int idx = tid; idx < NS * 32; idx += 256){
    int s = idx >> 5, hh = idx & 31;
    T[hh][s] = ctx[((size_t)b * NS + s) * NH + h0 + hh];
  }
  __syncthreads();
  int wv = tid >> 6, ln = tid & 63;
  double aev = (double)ae[b];
  double aw6[6], bt6[6]; double sbt = 0;
  #pragma unroll
  for (int i = 0; i < 6; ++i){
    aw6[i] = aw[b * NS + ln + 64 * i];
    bt6[i] = bt[b * NS + ln + 64 * i];
    sbt += bt6[i] * bt6[i];
  }
  double xnb = normclip(wredsumd(sbt));
  double art_xnb = artanh_(xnb);
  double denacc = 0.0;
  for (int k = 0; k < 8; ++k){
    int hh = wv * 8 + k;
    double v[6]; double sx = 0;
    #pragma unroll
    for (int i = 0; i < 6; ++i){ v[i] = (double)T[hh][ln + 64 * i]; sx += v[i] * v[i]; }
    double xnv = normclip(wredsumd(sx));
    double wx[6]; double swx = 0;
    #pragma unroll
    for (int i = 0; i < 6; ++i){ wx[i] = aw6[i] * v[i]; swx += wx[i] * wx[i]; }
    double wxn = normclip(wredsumd(swx));
    double s1 = tanh(wxn / xnv * artanh_(xnv)) / wxn;
    double mix[6]; double sm = 0;
    #pragma unroll
    for (int i = 0; i < 6; ++i){ mix[i] = s1 * wx[i]; sm += mix[i] * mix[i]; }
    double n1 = normclip(wredsumd(sm));
    if (n1 > 0.999){ double f = 0.999 / n1;
      #pragma unroll
      for (int i = 0; i < 6; ++i) mix[i] *= f; }
    double sm2 = 0;
    #pragma unroll
    for (int i = 0; i < 6; ++i) sm2 += mix[i] * mix[i];
    double xn2 = normclip(wredsumd(sm2));
    double wx2[6]; double sw2 = 0;
    #pragma unroll
    for (int i = 0; i < 6; ++i){ wx2[i] = aev * mix[i]; sw2 += wx2[i] * wx2[i]; }
    double wxn2 = normclip(wredsumd(sw2));
    double s2 = tanh(wxn2 / xn2 * artanh_(xn2)) / wxn2;
    double tmp[6]; double st = 0;
    #pragma unroll
    for (int i = 0; i < 6; ++i){ tmp[i] = s2 * wx2[i]; st += tmp[i] * tmp[i]; }
    double n2 = normclip(wredsumd(st));
    if (n2 > 0.999){ double f = 0.999 / n2;
      #pragma unroll
      for (int i = 0; i < 6; ++i) tmp[i] *= f; }
    double wx3[6]; double sw3 = 0;
    #pragma unroll
    for (int i = 0; i < 6; ++i){ wx3[i] = tmp[i] * bt6[i]; sw3 += wx3[i] * wx3[i]; }
    double wxn3 = normclip(wredsumd(sw3));
    double s3 = tanh(wxn3 / xnb * art_xnb) / wxn3;
    double t2[6]; double st2 = 0;
    #pragma unroll
    for (int i = 0; i < 6; ++i){ t2[i] = s3 * wx3[i]; st2 += t2[i] * t2[i]; }
    double n3 = normclip(wredsumd(st2));
    if (n3 > 0.999){ double f = 0.999 / n3;
      #pragma unroll
      for (int i = 0; i < 6; ++i) t2[i] *= f; }
    #pragma unroll
    for (int i = 0; i < 6; ++i) t2[i] = fmax(t2[i], 0.0);
    double sxx = 0, syy = 0, sxy = 0;
    #pragma unroll
    for (int i = 0; i < 6; ++i){ sxx += mix[i] * mix[i]; syy += t2[i] * t2[i]; sxy += mix[i] * t2[i]; }
    sxx = wredsumd(sxx); syy = wredsumd(syy); sxy = wredsumd(sxy);
    double dn = fmax(1.0 + 2.0 * sxy + sxx * syy, 1e-15);
    double ca = (1.0 + 2.0 * sxy + syy) / dn, cb = (1.0 - sxx) / dn;
    double m2[6]; double sm3 = 0;
    #pragma unroll
    for (int i = 0; i < 6; ++i){ m2[i] = ca * mix[i] + cb * t2[i]; sm3 += m2[i] * m2[i]; }
    double n4 = normclip(wredsumd(sm3));
    if (n4 > 0.999){ double f = 0.999 / n4;
      #pragma unroll
      for (int i = 0; i < 6; ++i) m2[i] *= f; }
    double snn = 0;
    #pragma unroll
    for (int i = 0; i < 6; ++i) snn += m2[i] * m2[i];
    snn = wredsumd(snn);
    double lam = 2.0 / fmax(1.0 - snn, 1e-15);
    #pragma unroll
    for (int i = 0; i < 6; ++i) atomicAdd(&nom[b * NS + ln + 64 * i], lam * m2[i]);
    if (ln == 0) denacc += lam - 1.0;
  }
  if (ln == 0) atomicAdd(&den[b], denacc);
}

// ---------------- midpoint + logmap0 + output head, one block per b ----------------
__global__ __launch_bounds__(256) void kfinal(const double* __restrict__ nom,
    const double* __restrict__ den, const double* __restrict__ query,
    const float* __restrict__ Wout, const float* __restrict__ W1,
    const float* __restrict__ b1, const float* __restrict__ W2,
    const float* __restrict__ b2, float* __restrict__ out)
{
  int b = blockIdx.x; int tid = threadIdx.x;
  __shared__ double comb[768];
  __shared__ double att[NH];
  __shared__ double x1[NH];
  __shared__ double red[4];
  double dnb = fmax(den[b], 1e-10);
  double u0 = nom[b * NS + tid] / dnb;
  double u1 = (tid + 256 < NS) ? nom[b * NS + tid + 256] / dnb : 0.0;
  double n = normclip(blocksumd(u0 * u0 + u1 * u1, red));
  double sf = tanh(0.5 * artanh_(n)) / n;
  double f0 = sf * u0, f1 = sf * u1;
  double n2 = normclip(blocksumd(f0 * f0 + f1 * f1, red));
  double sl = artanh_(n2) / n2;
  comb[tid] = sl * f0;
  if (tid + 256 < NS) comb[tid + 256] = sl * f1;
  for (int r = tid; r < NH; r += 256) comb[NH + r] = query[b * NH + r];
  __syncthreads();
  for (int r = tid; r < NH; r += 256){
    double s = 0;
    const float* wr = Wout + (size_t)r * 768;
    for (int c = 0; c < 768; ++c) s += comb[c] * (double)wr[c];
    att[r] = tanh(s);
  }
  __syncthreads();
  for (int r = tid; r < NH; r += 256){
    double s = (double)b1[r];
    const float* wr = W1 + (size_t)r * NH;
    for (int c = 0; c < NH; ++c) s += att[c] * (double)wr[c];
    x1[r] = fmax(s, 0.0);
  }
  __syncthreads();
  double p0 = 0, p1 = 0;
  for (int c = tid; c < NH; c += 256){ p0 += x1[c] * (double)W2[c]; p1 += x1[c] * (double)W2[NH + c]; }
  p0 = blocksumd(p0, red);
  p1 = blocksumd(p1, red);
  if (tid == 0){ out[b * 2 + 0] = (float)(p0 + (double)b2[0]); out[b * 2 + 1] = (float)(p1 + (double)b2[1]); }
}

extern "C" void kernel_launch(void* const* d_in, const int* in_sizes, int n_in,
                              void* d_out, int out_size, void* d_ws, size_t ws_size,
                              hipStream_t stream)
{
  const float* inputs  = (const float*)d_in[0];
  const float* tstamps = (const float*)d_in[1];
  const float* delta_t = (const float*)d_in[2];
  const float* W_all   = (const float*)d_in[3];
  const float* U_all   = (const float*)d_in[4];
  const float* W_d     = (const float*)d_in[5];
  const float* Win     = (const float*)d_in[6];
  const float* Wout    = (const float*)d_in[7];
  const float* ae      = (const float*)d_in[8];
  const float* ab      = (const float*)d_in[9];
  const float* W1      = (const float*)d_in[10];
  const float* b1      = (const float*)d_in[11];
  const float* W2      = (const float*)d_in[12];
  const float* b2      = (const float*)d_in[13];
  float* out = (float*)d_out;

  // double region (base 256B-aligned)
  double* wd = (double*)d_ws;
  size_t od = 0;
  double* NOMD  = wd + od; od += (size_t)NB * NS;
  double* DEND  = wd + od; od += (size_t)NB;
  double* QUERY = wd + od; od += (size_t)NB * NH;
  double* AW    = wd + od; od += (size_t)NB * NS;
  double* BT    = wd + od; od += (size_t)NB * NS;
  float* wf = (float*)(wd + od);
  size_t of = 0;
  float* WT   = wf + of; of += (size_t)NH * NZCOL;    // 1,327,104
  float* Zb   = wf + of; of += (size_t)NB * NZCOL;    // 442,368
  float* Hs32 = wf + of; of += (size_t)NB * NH;
  float* CCs32= wf + of; of += (size_t)NB * NH;
  float* CTX  = wf + of; of += (size_t)NB * NS * NH;  // 18,874,368
  unsigned* FLAGS = (unsigned*)(wf + of);             // (216+128)*32 u32
  int nflags = (NPROD + NKNL) * FSTRIDE;

  // zero NOMD..DEND (doubles), Hs/CCs (floats), flags
  int nzd = NB * NS + NB;
  hipLaunchKernelGGL(kzerod, dim3((nzd + 255) / 256), dim3(256), 0, stream, NOMD, nzd);
  int nzf = NB * NH * 2;
  hipLaunchKernelGGL(kzerof, dim3((nzf + 255) / 256), dim3(256), 0, stream, Hs32, nzf);
  hipLaunchKernelGGL(kzerof, dim3((nflags + 255) / 256), dim3(256), 0, stream,
                     (float*)FLAGS, nflags);

  int nprep = NH * NZCOL;
  hipLaunchKernelGGL(kprep, dim3((nprep + 255) / 256), dim3(256), 0, stream,
                     W_all, W_d, U_all, WT);

  // fused persistent scan (cooperative: 216 wgs co-resident, 1/CU)
  {
    const float* wt_ = WT;
    float* hs_ = Hs32; float* cc_ = CCs32; float* zb_ = Zb; float* ctx_ = CTX;
    const float* xin_ = inputs; const float* tst_ = tstamps;
    unsigned* flg_ = FLAGS;
    void* args[8] = { &wt_, &hs_, &cc_, &zb_, &ctx_, &xin_, &tst_, &flg_ };
    hipLaunchCooperativeKernel((const void*)kscan, dim3(NPROD), dim3(TPB), args, 0, stream);
  }

  hipLaunchKernelGGL(kattn1, dim3(128), dim3(256), 0, stream,
                     Hs32, Win, CTX, delta_t, ab, QUERY, AW, BT);
  hipLaunchKernelGGL(kmix, dim3(12, 128), dim3(256), 0, stream, CTX, AW, BT, ae, NOMD, DEND);
  hipLaunchKernelGGL(kfinal, dim3(128), dim3(256), 0, stream,
                     NOMD, DEND, QUERY, Wout, W1, b1, W2, b2, out);
}

// Round 7
// 30167.474 us; speedup vs baseline: 1.2652x; 1.1066x over previous
//
#include <hip/hip_runtime.h>
#include <cmath>

constexpr int NB = 128;     // batch
constexpr int NS = 384;     // seq len
constexpr int NH = 384;     // hidden = input dim
constexpr int NG4 = 1536;

__device__ __forceinline__ double clampd(double x, double lo, double hi){ return fmin(fmax(x,lo),hi); }
__device__ __forceinline__ double artanh_(double x){ return atanh(clampd(x, -1.0 + 1e-7, 1.0 - 1e-7)); }
__device__ __forceinline__ double normclip(double s){ return sqrt(fmax(s, 1e-15)); }
__device__ __forceinline__ double wredsumd(double v){
  #pragma unroll
  for (int off = 32; off; off >>= 1) v += __shfl_xor(v, off, 64);
  return v;
}

// ---------------- zero ----------------
__global__ void kzerod(double* p, int n){
  int i = blockIdx.x * 256 + threadIdx.x;
  if (i < n) p[i] = 0.0;
}

// ---------------- pack weights ----------------
// WTR[c][j], j in [0,1920): gates (W_all) then W_d.  WTU[c][jj], jj in [0,1536): U_all.
__global__ void kprep(const float* __restrict__ W_all, const float* __restrict__ W_d,
                      const float* __restrict__ U_all, float* __restrict__ WTR,
                      float* __restrict__ WTU)
{
  int i = blockIdx.x * 256 + threadIdx.x;
  const int nR = NH * 1920;       // 737,280
  const int nU = NH * 1536;       // 589,824
  if (i < nR){
    int c = i / 1920, j = i % 1920;
    float v;
    if (j < NG4){ int g = j / NH, r = j % NH; v = W_all[r * 1536 + g * NH + c]; }
    else { int r = j - NG4; v = W_d[r * NH + c]; }
    WTR[i] = v;
  } else if (i < nR + nU){
    int k = i - nR; int c = k / 1536, jj = k % 1536;
    int g = jj / NH, r = jj % NH;
    WTU[k] = U_all[(g * NH + r) * NH + c];
  }
}

// ---------------- one-time Q GEMM: Q[bs][jj] = sum_c X[bs][c] * WTU[c][jj] ----------------
// X = inputs [49152 x 384]; Q [49152 x 1536]. grid (24, 768), block 256; tile 64x64,
// K-chunk 32, thread 4x4; fp32 FMA + fp64 chunk-sum (identical chunking to scan GEMM).
__global__ __launch_bounds__(256) void kqgemm(const float* __restrict__ X,
    const float* __restrict__ Bw, float* __restrict__ Q)
{
  int j0 = blockIdx.x * 64, i0 = blockIdx.y * 64;
  __shared__ float As[32][68];
  __shared__ float Bs[32][64];
  int tid = threadIdx.x;
  int tn = tid & 15, tm = tid >> 4;
  int slm = tid >> 2;
  int slc = (tid & 3) * 8;
  int blk = tid >> 3;
  int bln = (tid & 7) * 8;
  double accd[4][4] = {{0.0}};
  const float* arow = X + (size_t)(i0 + slm) * NH;
  for (int c0 = 0; c0 < NH; c0 += 32){
    float4 a4 = *(const float4*)(arow + c0 + slc);
    float4 a4b = *(const float4*)(arow + c0 + slc + 4);
    As[slc+0][slm] = a4.x;  As[slc+1][slm] = a4.y;
    As[slc+2][slm] = a4.z;  As[slc+3][slm] = a4.w;
    As[slc+4][slm] = a4b.x; As[slc+5][slm] = a4b.y;
    As[slc+6][slm] = a4b.z; As[slc+7][slm] = a4b.w;
    const float* bp = Bw + (size_t)(c0 + blk) * 1536 + j0 + bln;
    float4 b4a = *(const float4*)bp;
    float4 b4b = *(const float4*)(bp + 4);
    *(float4*)&Bs[blk][bln] = b4a;
    *(float4*)&Bs[blk][bln+4] = b4b;
    __syncthreads();
    float acc[4][4] = {{0.f}};
    #pragma unroll 8
    for (int c = 0; c < 32; ++c){
      float4 av = *(const float4*)&As[c][tm*4];
      float4 bv = *(const float4*)&Bs[c][tn*4];
      float a[4] = {av.x, av.y, av.z, av.w};
      float bb[4] = {bv.x, bv.y, bv.z, bv.w};
      #pragma unroll
      for (int mm = 0; mm < 4; ++mm)
        #pragma unroll
        for (int jj = 0; jj < 4; ++jj)
          acc[mm][jj] += a[mm] * bb[jj];
    }
    __syncthreads();
    #pragma unroll
    for (int mm = 0; mm < 4; ++mm)
      #pragma unroll
      for (int jj = 0; jj < 4; ++jj) accd[mm][jj] += (double)acc[mm][jj];
  }
  #pragma unroll
  for (int mm = 0; mm < 4; ++mm){
    float4 o; o.x = (float)accd[mm][0]; o.y = (float)accd[mm][1];
    o.z = (float)accd[mm][2]; o.w = (float)accd[mm][3];
    *(float4*)(Q + (size_t)(i0 + tm*4 + mm) * 1536 + j0 + tn*4) = o;
  }
}

// ---------------- per-step nonlinear, one wave per batch row (device fn) ----------------
// zb: z row (p at [g*384+r], mv at [1536+r]); qb: U@x gate row; hrow/crow: LDS state rows.
__device__ void knl_wave(int ln, int b, int t, const float* zb, const float* qb,
    float* hrow, float* crow, float* __restrict__ ctx,
    const float* xrow, const float* __restrict__ tstamps)
{
  double ts = (double)tstamps[b * NS + t];
  float tsf = (float)ts;

  float cc6[6], mv6[6];
  double s_cc = 0, s_h = 0, s_mv = 0, s_x = 0;
  #pragma unroll
  for (int i = 0; i < 6; ++i){
    int r = ln + 64 * i;
    float c_ = crow[r]; cc6[i] = c_; s_cc += (double)c_ * c_;
    float h_ = hrow[r]; s_h += (double)h_ * h_;
    float m_ = zb[NG4 + r]; mv6[i] = m_; s_mv += (double)m_ * m_;
    float x_ = xrow[r]; s_x += (double)x_ * x_;
  }
  double cc2 = wredsumd(s_cc);  double cn = normclip(cc2);
  double hn  = normclip(wredsumd(s_h));
  double mvn = normclip(wredsumd(s_mv));
  double xn  = normclip(wredsumd(s_x));

  // ---- c path ----
  double s1 = tanh(mvn / cn * artanh_(cn));
  float c1f = (float)(s1 / mvn);
  float m1[6]; double sm1 = 0;
  #pragma unroll
  for (int i = 0; i < 6; ++i){ m1[i] = c1f * mv6[i]; sm1 += (double)m1[i] * m1[i]; }
  double n1 = normclip(wredsumd(sm1));
  float l1f = (float)(artanh_(n1) / n1);
  float v6[6]; double sv = 0;
  #pragma unroll
  for (int i = 0; i < 6; ++i){ v6[i] = tanhf(l1f * m1[i]); sv += (double)v6[i] * v6[i]; }
  double nv = normclip(wredsumd(sv));
  float e1f = (float)(tanh(nv) / nv);
  float cs1[6]; double scs = 0, sccd = 0;
  #pragma unroll
  for (int i = 0; i < 6; ++i){ cs1[i] = e1f * v6[i]; scs += (double)cs1[i] * cs1[i]; sccd -= (double)cs1[i] * cc6[i]; }

  double xnt = sqrt(fmax(384.0 * ts * ts, 1e-15));
  double swx = 0;
  #pragma unroll
  for (int i = 0; i < 6; ++i){ float w = cs1[i] * tsf; swx += (double)w * w; }
  double wxn1 = normclip(wredsumd(swx));
  double s2c = tanh(wxn1 / xnt * artanh_(xnt)) / wxn1;
  float s2f = (float)(s2c * ts);
  float cs2[6];
  #pragma unroll
  for (int i = 0; i < 6; ++i) cs2[i] = s2f * cs1[i];

  double x2a = wredsumd(scs);
  double xya = wredsumd(sccd);
  double y2a = cc2;
  double dA = fmax(1.0 + 2.0 * xya + x2a * y2a, 1e-15);
  float fXA = (float)((1.0 + 2.0 * xya + y2a) / dA);
  float fYA = (float)((1.0 - x2a) / dA);
  float A6[6]; double sA = 0, sAc = 0, sc2 = 0;
  #pragma unroll
  for (int i = 0; i < 6; ++i){
    A6[i] = fXA * (-cs1[i]) + fYA * cc6[i];
    sA += (double)A6[i] * A6[i]; sAc += (double)A6[i] * cs2[i]; sc2 += (double)cs2[i] * cs2[i];
  }
  double x2b = wredsumd(sA), xyb = wredsumd(sAc), y2b = wredsumd(sc2);
  double dB = fmax(1.0 + 2.0 * xyb + x2b * y2b, 1e-15);
  float fXB = (float)((1.0 + 2.0 * xyb + y2b) / dB);
  float fYB = (float)((1.0 - x2b) / dB);
  float cadj[6];
  #pragma unroll
  for (int i = 0; i < 6; ++i) cadj[i] = fXB * A6[i] + fYB * cs2[i];

  // ---- gates f,i,o,ct ----
  double art_hn = artanh_(hn), art_xn = artanh_(xn);
  float gates[4][6];
  #pragma unroll
  for (int g = 0; g < 4; ++g){
    float pg[6], qg[6]; double s_p = 0, s_q = 0;
    #pragma unroll
    for (int i = 0; i < 6; ++i){
      int r = ln + 64 * i;
      pg[i] = zb[g * NH + r];  s_p += (double)pg[i] * pg[i];
      qg[i] = qb[g * NH + r];  s_q += (double)qg[i] * qg[i];
    }
    double pn = normclip(wredsumd(s_p));
    double qn = normclip(wredsumd(s_q));
    float saf = (float)(tanh(pn / hn * art_hn) / pn);
    float sbf = (float)(tanh(qn / xn * art_xn) / qn);
    float a6[6], b6[6]; double sx2 = 0, sy2 = 0, sxy = 0;
    #pragma unroll
    for (int i = 0; i < 6; ++i){
      a6[i] = saf * pg[i]; b6[i] = sbf * qg[i];
      sx2 += (double)a6[i] * a6[i]; sy2 += (double)b6[i] * b6[i]; sxy += (double)a6[i] * b6[i];
    }
    sx2 = wredsumd(sx2); sy2 = wredsumd(sy2); sxy = wredsumd(sxy);
    double dd = fmax(1.0 + 2.0 * sxy + sx2 * sy2, 1e-15);
    float fX = (float)((1.0 + 2.0 * sxy + sy2) / dd);
    float fY = (float)((1.0 - sx2) / dd);
    float m6[6]; double smm = 0;
    #pragma unroll
    for (int i = 0; i < 6; ++i){ m6[i] = fX * a6[i] + fY * b6[i]; smm += (double)m6[i] * m6[i]; }
    double nm = normclip(wredsumd(smm));
    float slf = (float)(artanh_(nm) / nm);
    #pragma unroll
    for (int i = 0; i < 6; ++i) gates[g][i] = 1.f / (1.f + expf(-slf * m6[i]));
  }

  // ---- cc_n = mobius_add(pw(i,ct), pw(f,c_adj)) ----
  double sct = 0, sict = 0; float wP[6];
  #pragma unroll
  for (int i = 0; i < 6; ++i){ float ct = gates[3][i]; sct += (double)ct * ct; wP[i] = gates[1][i] * ct; sict += (double)wP[i] * wP[i]; }
  double ctn = normclip(wredsumd(sct));
  double wPn = normclip(wredsumd(sict));
  float sPf = (float)(tanh(wPn / ctn * artanh_(ctn)) / wPn);
  float P6[6]; double sPP = 0;
  #pragma unroll
  for (int i = 0; i < 6; ++i){ P6[i] = sPf * wP[i]; sPP += (double)P6[i] * P6[i]; }
  double sca = 0, sfca = 0; float wQ[6];
  #pragma unroll
  for (int i = 0; i < 6; ++i){ sca += (double)cadj[i] * cadj[i]; wQ[i] = gates[0][i] * cadj[i]; sfca += (double)wQ[i] * wQ[i]; }
  double can = normclip(wredsumd(sca));
  double wQn = normclip(wredsumd(sfca));
  float sQf = (float)(tanh(wQn / can * artanh_(can)) / wQn);
  float Q6[6]; double sQQ = 0, sPQ = 0;
  #pragma unroll
  for (int i = 0; i < 6; ++i){ Q6[i] = sQf * wQ[i]; sQQ += (double)Q6[i] * Q6[i]; sPQ += (double)P6[i] * Q6[i]; }
  double x2c = wredsumd(sPP), y2c = wredsumd(sQQ), xyc = wredsumd(sPQ);
  double dC = fmax(1.0 + 2.0 * xyc + x2c * y2c, 1e-15);
  float fXC = (float)((1.0 + 2.0 * xyc + y2c) / dC);
  float fYC = (float)((1.0 - x2c) / dC);
  float ccn6[6], w6[6]; double sw_ = 0;
  #pragma unroll
  for (int i = 0; i < 6; ++i){ ccn6[i] = fXC * P6[i] + fYC * Q6[i]; w6[i] = tanhf(ccn6[i]); sw_ += (double)w6[i] * w6[i]; }
  double nw = normclip(wredsumd(sw_));
  float eef = (float)(tanh(nw) / nw);
  float e6[6], wH[6]; double se = 0, soe = 0;
  #pragma unroll
  for (int i = 0; i < 6; ++i){ e6[i] = eef * w6[i]; se += (double)e6[i] * e6[i]; wH[i] = gates[2][i] * e6[i]; soe += (double)wH[i] * wH[i]; }
  double en = normclip(wredsumd(se));
  double wHn = normclip(wredsumd(soe));
  float sHf = (float)(tanh(wHn / en * artanh_(en)) / wHn);
  #pragma unroll
  for (int i = 0; i < 6; ++i){
    int r = ln + 64 * i;
    crow[r] = ccn6[i];
    hrow[r] = sHf * wH[i];
    ctx[((size_t)b * NS + t) * NH + r] = gates[2][i];
  }
}

// ---------------- scan: one wg owns 2 batch rows; ZERO inter-wg communication ----------------
// 64 wgs x 512 thr (regular launch). Per step: GEMM z[2][ncol] into LDS (weights from
// L2-resident WTR, A rows h/cc/x from LDS), __syncthreads, knl on waves 0/1, __syncthreads.
// usePre: q-gates from precomputed Qp (ncol=1920); else computed in-scan (ncol=3456).
__global__ __launch_bounds__(512) void kscan2(const float* __restrict__ WTR,
    const float* __restrict__ WTU, const float* __restrict__ Qp, int usePre,
    float* __restrict__ Hs, float* __restrict__ ctx,
    const float* __restrict__ xin, const float* __restrict__ tst)
{
  int tid = threadIdx.x;
  int b0 = blockIdx.x * 2;
  __shared__ float zsh[2][3472];
  __shared__ float hsh[2][NH], csh[2][NH], xsh[2][NH];
  int ncol = usePre ? 1920 : 3456;
  int ng4 = ncol >> 2;

  for (int u = tid; u < 2 * NH; u += 512){
    hsh[u / NH][u % NH] = 0.f;
    csh[u / NH][u % NH] = 0.f;
  }
  __syncthreads();

  for (int t = 0; t < NS; ++t){
    // stage x rows
    for (int u = tid; u < 2 * NH; u += 512){
      int rr = u / NH, r = u % NH;
      xsh[rr][r] = xin[((size_t)(b0 + rr) * NS + t) * NH + r];
    }
    __syncthreads();
    // GEMM: z[r][j0..j0+3] for both rows, 32-k fp32 chunks + fp64 chunk-sum
    for (int g4 = tid; g4 < ng4; g4 += 512){
      int j0 = g4 * 4;
      const float* wcol; int wstr;
      const float* arow0; const float* arow1;
      if (j0 < 1920){ wcol = WTR + j0; wstr = 1920; }
      else { wcol = WTU + (j0 - 1920); wstr = 1536; }
      if (j0 < NG4){ arow0 = hsh[0]; arow1 = hsh[1]; }
      else if (j0 < 1920){ arow0 = csh[0]; arow1 = csh[1]; }
      else { arow0 = xsh[0]; arow1 = xsh[1]; }
      double accd[2][4] = {{0.0}};
      for (int k0 = 0; k0 < NH; k0 += 32){
        float acc[2][4] = {{0.f}};
        #pragma unroll
        for (int kk = 0; kk < 32; ++kk){
          float4 w = *(const float4*)(wcol + (size_t)(k0 + kk) * wstr);
          float a0 = arow0[k0 + kk], a1 = arow1[k0 + kk];
          acc[0][0] += a0 * w.x; acc[0][1] += a0 * w.y;
          acc[0][2] += a0 * w.z; acc[0][3] += a0 * w.w;
          acc[1][0] += a1 * w.x; acc[1][1] += a1 * w.y;
          acc[1][2] += a1 * w.z; acc[1][3] += a1 * w.w;
        }
        #pragma unroll
        for (int rr = 0; rr < 2; ++rr)
          #pragma unroll
          for (int jj = 0; jj < 4; ++jj) accd[rr][jj] += (double)acc[rr][jj];
      }
      #pragma unroll
      for (int rr = 0; rr < 2; ++rr){
        float4 o; o.x = (float)accd[rr][0]; o.y = (float)accd[rr][1];
        o.z = (float)accd[rr][2]; o.w = (float)accd[rr][3];
        *(float4*)&zsh[rr][j0] = o;
      }
    }
    __syncthreads();
    // knl: waves 0,1 -> rows b0, b0+1
    if (tid < 128){
      int wv = tid >> 6, ln = tid & 63;
      const float* qb = usePre ? (Qp + ((size_t)(b0 + wv) * NS + t) * 1536)
                               : &zsh[wv][1920];
      knl_wave(ln, b0 + wv, t, zsh[wv], qb, hsh[wv], csh[wv], ctx, xsh[wv], tst);
    }
    __syncthreads();
  }
  // export final h for attention
  for (int u = tid; u < 2 * NH; u += 512){
    int rr = u / NH, r = u % NH;
    Hs[(size_t)(b0 + rr) * NH + r] = hsh[rr][r];
  }
}

// ---------------- block reduce helpers (256 threads / 4 waves), double ----------------
__device__ __forceinline__ double blocksumd(double v, double* red){
  v = wredsumd(v);
  __syncthreads();
  if ((threadIdx.x & 63) == 0) red[threadIdx.x >> 6] = v;
  __syncthreads();
  return red[0] + red[1] + red[2] + red[3];
}
__device__ __forceinline__ double blockmaxd(double v, double* red){
  #pragma unroll
  for (int off = 32; off; off >>= 1) v = fmax(v, __shfl_xor(v, off, 64));
  __syncthreads();
  if ((threadIdx.x & 63) == 0) red[threadIdx.x >> 6] = v;
  __syncthreads();
  return fmax(fmax(red[0], red[1]), fmax(red[2], red[3]));
}

// ---------------- query / scores / softmax / aw / bt (one block per b) ----------------
__global__ __launch_bounds__(256) void kattn1(const float* __restrict__ Hs,
    const float* __restrict__ Win, const float* __restrict__ ctx,
    const float* __restrict__ dt, const float* __restrict__ ab,
    double* __restrict__ query, double* __restrict__ aw, double* __restrict__ bt)
{
  int b = blockIdx.x; int tid = threadIdx.x;
  __shared__ double hL[NH], qL[NH], sc[NS];
  __shared__ double red[4];
  for (int r = tid; r < NH; r += 256) hL[r] = (double)Hs[b * NH + r];
  __syncthreads();
  for (int r = tid; r < NH; r += 256){
    double s = 0;
    const float* wr = Win + (size_t)r * NH;
    for (int c = 0; c < NH; ++c) s += hL[c] * (double)wr[c];
    qL[r] = s; query[b * NH + r] = s;
  }
  __syncthreads();
  int wv = tid >> 6, ln = tid & 63;
  for (int s_ = wv; s_ < NS; s_ += 4){
    const float* crow = ctx + ((size_t)b * NS + s_) * NH;
    double par = 0;
    #pragma unroll
    for (int i = 0; i < 6; ++i){ int d = ln + 64 * i; par += qL[d] * (double)crow[d]; }
    par = wredsumd(par);
    if (ln == 0) sc[s_] = par;
  }
  __syncthreads();
  double v0 = sc[tid];
  double v1 = (tid + 256 < NS) ? sc[tid + 256] : -1e300;
  double mx = blockmaxd(fmax(v0, v1), red);
  double e0 = exp(v0 - mx);
  double e1 = (tid + 256 < NS) ? exp(v1 - mx) : 0.0;
  double tot = blocksumd(e0 + e1, red);
  double a0 = e0 / tot, a1 = e1 / tot;
  double n = normclip(blocksumd(a0 * a0 + a1 * a1, red));
  double s1 = tanh(n) / n;
  double w0 = s1 * a0, w1 = s1 * a1;
  double pn = normclip(blocksumd(w0 * w0 + w1 * w1, red));
  if (pn > 0.999){ double f = 0.999 / pn; w0 *= f; w1 *= f; }
  aw[b * NS + tid] = w0;
  if (tid + 256 < NS) aw[b * NS + tid + 256] = w1;
  double abv = (double)ab[b];
  double b0 = exp(-abv * (double)dt[b * NS + tid]);
  double b1v = (tid + 256 < NS) ? exp(-abv * (double)dt[b * NS + tid + 256]) : 0.0;
  double nb = normclip(blocksumd(b0 * b0 + b1v * b1v, red));
  double sb = tanh(nb) / nb;
  double c0 = sb * b0, c1 = sb * b1v;
  double pnb = normclip(blocksumd(c0 * c0 + c1 * c1, red));
  if (pnb > 0.999){ double f = 0.999 / pnb; c0 *= f; c1 *= f; }
  bt[b * NS + tid] = c0;
  if (tid + 256 < NS) bt[b * NS + tid + 256] = c1;
}

// ---------------- hyperbolic attention mixing, one block per (b, 32 h-rows) ----------------
__global__ __launch_bounds__(256) void kmix(const float* __restrict__ ctx,
    const double* __restrict__ aw, const double* __restrict__ bt,
    const float* __restrict__ ae, double* __restrict__ nom, double* __restrict__ den)
{
  int b = blockIdx.y; int h0 = blockIdx.x * 32;
  __shared__ float T[32][385];
  int tid = threadIdx.x;
  for (int idx = tid; idx < NS * 32; idx += 256){
    int s = idx >> 5, hh = idx & 31;
    T[hh][s] = ctx[((size_t)b * NS + s) * NH + h0 + hh];
  }
  __syncthreads();
  int wv = tid >> 6, ln = tid & 63;
  double aev = (double)ae[b];
  double aw6[6], bt6[6]; double sbt = 0;
  #pragma unroll
  for (int i = 0; i < 6; ++i){
    aw6[i] = aw[b * NS + ln + 64 * i];
    bt6[i] = bt[b * NS + ln + 64 * i];
    sbt += bt6[i] * bt6[i];
  }
  double xnb = normclip(wredsumd(sbt));
  double art_xnb = artanh_(xnb);
  double denacc = 0.0;
  for (int k = 0; k < 8; ++k){
    int hh = wv * 8 + k;
    double v[6]; double sx = 0;
    #pragma unroll
    for (int i = 0; i < 6; ++i){ v[i] = (double)T[hh][ln + 64 * i]; sx += v[i] * v[i]; }
    double xnv = normclip(wredsumd(sx));
    double wx[6]; double swx = 0;
    #pragma unroll
    for (int i = 0; i < 6; ++i){ wx[i] = aw6[i] * v[i]; swx += wx[i] * wx[i]; }
    double wxn = normclip(wredsumd(swx));
    double s1 = tanh(wxn / xnv * artanh_(xnv)) / wxn;
    double mix[6]; double sm = 0;
    #pragma unroll
    for (int i = 0; i < 6; ++i){ mix[i] = s1 * wx[i]; sm += mix[i] * mix[i]; }
    double n1 = normclip(wredsumd(sm));
    if (n1 > 0.999){ double f = 0.999 / n1;
      #pragma unroll
      for (int i = 0; i < 6; ++i) mix[i] *= f; }
    double sm2 = 0;
    #pragma unroll
    for (int i = 0; i < 6; ++i) sm2 += mix[i] * mix[i];
    double xn2 = normclip(wredsumd(sm2));
    double wx2[6]; double sw2 = 0;
    #pragma unroll
    for (int i = 0; i < 6; ++i){ wx2[i] = aev * mix[i]; sw2 += wx2[i] * wx2[i]; }
    double wxn2 = normclip(wredsumd(sw2));
    double s2 = tanh(wxn2 / xn2 * artanh_(xn2)) / wxn2;
    double tmp[6]; double st = 0;
    #pragma unroll
    for (int i = 0; i < 6; ++i){ tmp[i] = s2 * wx2[i]; st += tmp[i] * tmp[i]; }
    double n2 = normclip(wredsumd(st));
    if (n2 > 0.999){ double f = 0.999 / n2;
      #pragma unroll
      for (int i = 0; i < 6; ++i) tmp[i] *= f; }
    double wx3[6]; double sw3 = 0;
    #pragma unroll
    for (int i = 0; i < 6; ++i){ wx3[i] = tmp[i] * bt6[i]; sw3 += wx3[i] * wx3[i]; }
    double wxn3 = normclip(wredsumd(sw3));
    double s3 = tanh(wxn3 / xnb * art_xnb) / wxn3;
    double t2[6]; double st2 = 0;
    #pragma unroll
    for (int i = 0; i < 6; ++i){ t2[i] = s3 * wx3[i]; st2 += t2[i] * t2[i]; }
    double n3 = normclip(wredsumd(st2));
    if (n3 > 0.999){ double f = 0.999 / n3;
      #pragma unroll
      for (int i = 0; i < 6; ++i) t2[i] *= f; }
    #pragma unroll
    for (int i = 0; i < 6; ++i) t2[i] = fmax(t2[i], 0.0);
    double sxx = 0, syy = 0, sxy = 0;
    #pragma unroll
    for (int i = 0; i < 6; ++i){ sxx += mix[i] * mix[i]; syy += t2[i] * t2[i]; sxy += mix[i] * t2[i]; }
    sxx = wredsumd(sxx); syy = wredsumd(syy); sxy = wredsumd(sxy);
    double dn = fmax(1.0 + 2.0 * sxy + sxx * syy, 1e-15);
    double ca = (1.0 + 2.0 * sxy + syy) / dn, cb = (1.0 - sxx) / dn;
    double m2[6]; double sm3 = 0;
    #pragma unroll
    for (int i = 0; i < 6; ++i){ m2[i] = ca * mix[i] + cb * t2[i]; sm3 += m2[i] * m2[i]; }
    double n4 = normclip(wredsumd(sm3));
    if (n4 > 0.999){ double f = 0.999 / n4;
      #pragma unroll
      for (int i = 0; i < 6; ++i) m2[i] *= f; }
    double snn = 0;
    #pragma unroll
    for (int i = 0; i < 6; ++i) snn += m2[i] * m2[i];
    snn = wredsumd(snn);
    double lam = 2.0 / fmax(1.0 - snn, 1e-15);
    #pragma unroll
    for (int i = 0; i < 6; ++i) atomicAdd(&nom[b * NS + ln + 64 * i], lam * m2[i]);
    if (ln == 0) denacc += lam - 1.0;
  }
  if (ln == 0) atomicAdd(&den[b], denacc);
}

// ---------------- midpoint + logmap0 + output head, one block per b ----------------
__global__ __launch_bounds__(256) void kfinal(const double* __restrict__ nom,
    const double* __restrict__ den, const double* __restrict__ query,
    const float* __restrict__ Wout, const float* __restrict__ W1,
    const float* __restrict__ b1, const float* __restrict__ W2,
    const float* __restrict__ b2, float* __restrict__ out)
{
  int b = blockIdx.x; int tid = threadIdx.x;
  __shared__ double comb[768];
  __shared__ double att[NH];
  __shared__ double x1[NH];
  __shared__ double red[4];
  double dnb = fmax(den[b], 1e-10);
  double u0 = nom[b * NS + tid] / dnb;
  double u1 = (tid + 256 < NS) ? nom[b * NS + tid + 256] / dnb : 0.0;
  double n = normclip(blocksumd(u0 * u0 + u1 * u1, red));
  double sf = tanh(0.5 * artanh_(n)) / n;
  double f0 = sf * u0, f1 = sf * u1;
  double n2 = normclip(blocksumd(f0 * f0 + f1 * f1, red));
  double sl = artanh_(n2) / n2;
  comb[tid] = sl * f0;
  if (tid + 256 < NS) comb[tid + 256] = sl * f1;
  for (int r = tid; r < NH; r += 256) comb[NH + r] = query[b * NH + r];
  __syncthreads();
  for (int r = tid; r < NH; r += 256){
    double s = 0;
    const float* wr = Wout + (size_t)r * 768;
    for (int c = 0; c < 768; ++c) s += comb[c] * (double)wr[c];
    att[r] = tanh(s);
  }
  __syncthreads();
  for (int r = tid; r < NH; r += 256){
    double s = (double)b1[r];
    const float* wr = W1 + (size_t)r * NH;
    for (int c = 0; c < NH; ++c) s += att[c] * (double)wr[c];
    x1[r] = fmax(s, 0.0);
  }
  __syncthreads();
  double p0 = 0, p1 = 0;
  for (int c = tid; c < NH; c += 256){ p0 += x1[c] * (double)W2[c]; p1 += x1[c] * (double)W2[NH + c]; }
  p0 = blocksumd(p0, red);
  p1 = blocksumd(p1, red);
  if (tid == 0){ out[b * 2 + 0] = (float)(p0 + (double)b2[0]); out[b * 2 + 1] = (float)(p1 + (double)b2[1]); }
}

extern "C" void kernel_launch(void* const* d_in, const int* in_sizes, int n_in,
                              void* d_out, int out_size, void* d_ws, size_t ws_size,
                              hipStream_t stream)
{
  const float* inputs  = (const float*)d_in[0];
  const float* tstamps = (const float*)d_in[1];
  const float* delta_t = (const float*)d_in[2];
  const float* W_all   = (const float*)d_in[3];
  const float* U_all   = (const float*)d_in[4];
  const float* W_d     = (const float*)d_in[5];
  const float* Win     = (const float*)d_in[6];
  const float* Wout    = (const float*)d_in[7];
  const float* ae      = (const float*)d_in[8];
  const float* ab      = (const float*)d_in[9];
  const float* W1      = (const float*)d_in[10];
  const float* b1      = (const float*)d_in[11];
  const float* W2      = (const float*)d_in[12];
  const float* b2      = (const float*)d_in[13];
  float* out = (float*)d_out;

  // double region (base 256B-aligned)
  double* wd = (double*)d_ws;
  size_t od = 0;
  double* NOMD  = wd + od; od += (size_t)NB * NS;
  double* DEND  = wd + od; od += (size_t)NB;
  double* QUERY = wd + od; od += (size_t)NB * NH;
  double* AW    = wd + od; od += (size_t)NB * NS;
  double* BT    = wd + od; od += (size_t)NB * NS;
  float* wf = (float*)(wd + od);
  size_t of = 0;
  float* WTR  = wf + of; of += (size_t)NH * 1920;     //   737,280
  float* WTU  = wf + of; of += (size_t)NH * 1536;     //   589,824
  float* Hs32 = wf + of; of += (size_t)NB * NH;       //    49,152
  float* CTX  = wf + of; of += (size_t)NB * NS * NH;  // 18,874,368
  float* Qp   = wf + of;                              // optional 75,497,472

  size_t bytes_base = od * 8 + of * 4;
  size_t bytes_q = (size_t)NB * NS * 1536 * 4;        // 302 MB
  int usePre = (ws_size >= bytes_base + bytes_q) ? 1 : 0;

  // zero NOM/DEN (contiguous doubles)
  int nzd = NB * NS + NB;
  hipLaunchKernelGGL(kzerod, dim3((nzd + 255) / 256), dim3(256), 0, stream, NOMD, nzd);

  int nprep = NH * 1920 + NH * 1536;
  hipLaunchKernelGGL(kprep, dim3((nprep + 255) / 256), dim3(256), 0, stream,
                     W_all, W_d, U_all, WTR, WTU);

  if (usePre)
    hipLaunchKernelGGL(kqgemm, dim3(24, 768), dim3(256), 0, stream, inputs, WTU, Qp);

  hipLaunchKernelGGL(kscan2, dim3(64), dim3(512), 0, stream,
                     WTR, WTU, Qp, usePre, Hs32, CTX, inputs, tstamps);

  hipLaunchKernelGGL(kattn1, dim3(128), dim3(256), 0, stream,
                     Hs32, Win, CTX, delta_t, ab, QUERY, AW, BT);
  hipLaunchKernelGGL(kmix, dim3(12, 128), dim3(256), 0, stream, CTX, AW, BT, ae, NOMD, DEND);
  hipLaunchKernelGGL(kfinal, dim3(128), dim3(256), 0, stream,
                     NOMD, DEND, QUERY, Wout, W1, b1, W2, b2, out);
}